// Round 1
// baseline (5471.696 us; speedup 1.0000x reference)
//
#include <hip/hip_runtime.h>
#include <math.h>

#define N_NODES 10000
#define N_EDGES 320000
#define D 64
#define D_IN 128
#define D_OUT 16
#define NM (N_NODES * D)   // 640000 elements per state vector

// ---------------------------------------------------------------------------
// Theta = (I + Om)^-1 (I - Om), Om = 0.5*(B - B^T).  One block, Gauss-Jordan
// with partial pivoting on the [64 x 128] augmented matrix in LDS.
// Stores Theta TRANSPOSED: thetaT[k*64 + d] = Theta[d][k]  (bank-friendly).
// ---------------------------------------------------------------------------
__global__ void theta_kernel(const float* __restrict__ B, float* __restrict__ thetaT) {
    __shared__ float M[64][129];
    __shared__ float fcol[64];
    __shared__ int   piv_s;
    __shared__ float inv_s;
    const int tid = threadIdx.x;

    for (int i = tid; i < 64 * 128; i += 256) {
        int r = i >> 7, c = i & 127;
        float v;
        if (c < 64) {
            float om = 0.5f * (B[r * 64 + c] - B[c * 64 + r]);
            v = om + (r == c ? 1.0f : 0.0f);
        } else {
            int c2 = c - 64;
            float om = 0.5f * (B[r * 64 + c2] - B[c2 * 64 + r]);
            v = -om + (r == c2 ? 1.0f : 0.0f);
        }
        M[r][c] = v;
    }
    __syncthreads();

    for (int k = 0; k < 64; k++) {
        if (tid == 0) {
            int p = k; float best = fabsf(M[k][k]);
            for (int r = k + 1; r < 64; r++) {
                float v = fabsf(M[r][k]);
                if (v > best) { best = v; p = r; }
            }
            piv_s = p;
        }
        __syncthreads();
        int p = piv_s;
        if (p != k) {
            for (int c = tid; c < 128; c += 256) {
                float tmp = M[k][c]; M[k][c] = M[p][c]; M[p][c] = tmp;
            }
        }
        __syncthreads();
        if (tid == 0) inv_s = 1.0f / M[k][k];
        __syncthreads();
        float invp = inv_s;
        for (int c = tid; c < 128; c += 256) M[k][c] *= invp;
        __syncthreads();
        for (int r = tid; r < 64; r += 256) fcol[r] = M[r][k];
        __syncthreads();
        for (int i = tid; i < 64 * 128; i += 256) {
            int r = i >> 7, c = i & 127;
            if (r != k) M[r][c] -= fcol[r] * M[k][c];
        }
        __syncthreads();
    }
    // right half is Theta; store transposed
    for (int i = tid; i < 64 * 64; i += 256) {
        int kk = i >> 6, d = i & 63;
        thetaT[i] = M[d][64 + kk];
    }
}

// ---------------------------------------------------------------------------
// b[node][d] = x[node] @ enc_W[:, d] + enc_b[d]   (node-major [N][64])
// ---------------------------------------------------------------------------
__global__ void enc_kernel(const float* __restrict__ x, const float* __restrict__ W,
                           const float* __restrict__ bias, float* __restrict__ b) {
    __shared__ float xrow[D_IN];
    const int node = blockIdx.x, tid = threadIdx.x;   // 64 threads
    xrow[tid]      = x[node * D_IN + tid];
    xrow[tid + 64] = x[node * D_IN + tid + 64];
    __syncthreads();
    float acc = bias[tid];
#pragma unroll
    for (int k = 0; k < D_IN; k++) acc = fmaf(xrow[k], W[k * D + tid], acc);
    b[node * D + tid] = acc;
}

// ---------------------------------------------------------------------------
// t = |u| + b      (2*relu(u) - u == |u|; ALPHA == 1)
// ---------------------------------------------------------------------------
__global__ void tmap_kernel(const float* __restrict__ u, const float* __restrict__ b,
                            float* __restrict__ t) {
    int i = blockIdx.x * blockDim.x + threadIdx.x;
    if (i >= NM / 4) return;
    const float4 uv = ((const float4*)u)[i];
    const float4 bv = ((const float4*)b)[i];
    float4 r;
    r.x = fabsf(uv.x) + bv.x;
    r.y = fabsf(uv.y) + bv.y;
    r.z = fabsf(uv.z) + bv.z;
    r.w = fabsf(uv.w) + bv.w;
    ((float4*)t)[i] = r;
}

// ---------------------------------------------------------------------------
// S[dst][c] += w * t[src][c]   edge-parallel, 16 lanes/edge, float4 gather
// ---------------------------------------------------------------------------
__global__ void spmm_kernel(const int* __restrict__ src, const int* __restrict__ dst,
                            const float* __restrict__ ew, const float* __restrict__ t,
                            float* __restrict__ S) {
    int idx = blockIdx.x * blockDim.x + threadIdx.x;
    const int total = N_EDGES * 16;
    const int stride = gridDim.x * blockDim.x;
    for (; idx < total; idx += stride) {
        int e = idx >> 4;
        int c = (idx & 15) << 2;
        int s = src[e], d = dst[e];
        float w = ew[e];
        const float4 v = *(const float4*)(t + s * D + c);
        float* o = S + d * D + c;
        atomicAdd(o + 0, w * v.x);
        atomicAdd(o + 1, w * v.y);
        atomicAdd(o + 2, w * v.z);
        atomicAdd(o + 3, w * v.w);
    }
}

// ---------------------------------------------------------------------------
// out[node][d] = b[node][d] + 0.5 * sum_k S[node][k] * ThetaT[k][d]
// 4 nodes per 256-thread block; Theta^T staged in LDS (conflict-free reads).
// ---------------------------------------------------------------------------
__global__ void apply_kernel(const float* __restrict__ S, const float* __restrict__ b,
                             const float* __restrict__ thetaT, float* __restrict__ out) {
    __shared__ float Th[D * D];
    __shared__ float Srow[4][D];
    const int tid = threadIdx.x;
    for (int i = tid; i < D * D; i += 256) Th[i] = thetaT[i];
    const int ln = tid & 63, nn = tid >> 6;
    const int node = blockIdx.x * 4 + nn;
    Srow[nn][ln] = S[node * D + ln];
    __syncthreads();
    float acc = 0.0f;
#pragma unroll
    for (int k = 0; k < D; k++) acc = fmaf(Srow[nn][k], Th[k * D + ln], acc);
    out[node * D + ln] = b[node * D + ln] + 0.5f * acc;
}

// ---------------------------------------------------------------------------
// Anderson: GG upper triangle (15 entries) of (F-X)(F-X)^T in double.
// ---------------------------------------------------------------------------
__global__ void gg_kernel(const float* __restrict__ Xb, const float* __restrict__ Fb,
                          double* __restrict__ GG) {
    double acc[15];
#pragma unroll
    for (int p = 0; p < 15; p++) acc[p] = 0.0;
    int idx = blockIdx.x * blockDim.x + threadIdx.x;
    const int stride = gridDim.x * blockDim.x;
    for (int i = idx; i < NM; i += stride) {
        float g[5];
#pragma unroll
        for (int j = 0; j < 5; j++) g[j] = Fb[j * NM + i] - Xb[j * NM + i];
        int p = 0;
#pragma unroll
        for (int a = 0; a < 5; a++)
#pragma unroll
            for (int bq = a; bq < 5; bq++) acc[p++] += (double)g[a] * (double)g[bq];
    }
#pragma unroll
    for (int p = 0; p < 15; p++)
        for (int o = 32; o > 0; o >>= 1) acc[p] += __shfl_down(acc[p], o, 64);
    if ((threadIdx.x & 63) == 0) {
#pragma unroll
        for (int p = 0; p < 15; p++) atomicAdd(&GG[p], acc[p]);
    }
}

// ---------------------------------------------------------------------------
// a = (GG + lam I)^-1 1 ; a /= sum(a).  One thread, 5x5 in double.
// ---------------------------------------------------------------------------
__global__ void solve_kernel(const double* __restrict__ GG, float* __restrict__ a) {
    if (threadIdx.x != 0 || blockIdx.x != 0) return;
    double A[5][5], rhs[5];
    int p = 0;
    for (int r = 0; r < 5; r++)
        for (int c = r; c < 5; c++) { double v = GG[p++]; A[r][c] = v; A[c][r] = v; }
    for (int i = 0; i < 5; i++) { A[i][i] += 1e-4; rhs[i] = 1.0; }
    for (int i = 0; i < 5; i++) {
        int piv = i; double best = fabs(A[i][i]);
        for (int r = i + 1; r < 5; r++) {
            double v = fabs(A[r][i]);
            if (v > best) { best = v; piv = r; }
        }
        if (piv != i) {
            for (int c = 0; c < 5; c++) { double tmp = A[i][c]; A[i][c] = A[piv][c]; A[piv][c] = tmp; }
            double tr = rhs[i]; rhs[i] = rhs[piv]; rhs[piv] = tr;
        }
        double inv = 1.0 / A[i][i];
        for (int c = 0; c < 5; c++) A[i][c] *= inv;
        rhs[i] *= inv;
        for (int r = 0; r < 5; r++)
            if (r != i) {
                double f = A[r][i];
                for (int c = 0; c < 5; c++) A[r][c] -= f * A[i][c];
                rhs[r] -= f * rhs[i];
            }
    }
    double s = rhs[0] + rhs[1] + rhs[2] + rhs[3] + rhs[4];
    for (int j = 0; j < 5; j++) a[j] = (float)(rhs[j] / s);
}

// ---------------------------------------------------------------------------
// Xk = sum_j a[j] * F[j]
// ---------------------------------------------------------------------------
__global__ void combine_kernel(const float* __restrict__ Fb, const float* __restrict__ a,
                               float* __restrict__ Xk) {
    __shared__ float as[5];
    if (threadIdx.x < 5) as[threadIdx.x] = a[threadIdx.x];
    __syncthreads();
    int i = blockIdx.x * blockDim.x + threadIdx.x;
    if (i >= NM / 4) return;
    float4 r = {0.f, 0.f, 0.f, 0.f};
#pragma unroll
    for (int j = 0; j < 5; j++) {
        const float4 f = ((const float4*)(Fb + j * NM))[i];
        float aj = as[j];
        r.x = fmaf(aj, f.x, r.x);
        r.y = fmaf(aj, f.y, r.y);
        r.z = fmaf(aj, f.z, r.z);
        r.w = fmaf(aj, f.w, r.w);
    }
    ((float4*)Xk)[i] = r;
}

// ---------------------------------------------------------------------------
// out[node][o] = sum_d relu(u[node][d]) * decW[d][o]
// ---------------------------------------------------------------------------
__global__ void out_kernel(const float* __restrict__ u, const float* __restrict__ decW,
                           float* __restrict__ out) {
    __shared__ float W[D * D_OUT];
    __shared__ float rows[16][D + 1];
    const int tid = threadIdx.x;
    for (int i = tid; i < D * D_OUT; i += 256) W[i] = decW[i];
    const int node0 = blockIdx.x * 16;
    for (int i = tid; i < 16 * D; i += 256) {
        int n = i >> 6, d = i & 63;
        rows[n][d] = u[(node0 + n) * D + d];
    }
    __syncthreads();
    const int n = tid >> 4, o = tid & 15;
    float acc = 0.0f;
#pragma unroll
    for (int d2 = 0; d2 < D; d2++)
        acc = fmaf(fmaxf(rows[n][d2], 0.0f), W[d2 * D_OUT + o], acc);
    out[(node0 + n) * D_OUT + o] = acc;
}

// ---------------------------------------------------------------------------
extern "C" void kernel_launch(void* const* d_in, const int* in_sizes, int n_in,
                              void* d_out, int out_size, void* d_ws, size_t ws_size,
                              hipStream_t stream) {
    const float* x    = (const float*)d_in[0];
    const int*   ei   = (const int*)d_in[1];
    const float* ew   = (const float*)d_in[2];
    const float* encW = (const float*)d_in[3];
    const float* encb = (const float*)d_in[4];
    const float* cayB = (const float*)d_in[5];
    const float* decW = (const float*)d_in[6];
    float* out = (float*)d_out;
    const int* src = ei;
    const int* dst = ei + N_EDGES;

    char* w = (char*)d_ws;
    double* GG     = (double*)w;              // 15 used, 256 B reserved
    float*  avec   = (float*)(w + 256);       // 5 used
    float*  thetaT = (float*)(w + 512);       // 16384 B
    float*  b  = (float*)(w + 16896);
    float*  t  = b + NM;
    float*  S  = t + NM;
    float*  Xb = S + NM;                      // 5 slots
    float*  Fb = Xb + 5 * NM;                 // 5 slots

    theta_kernel<<<1, 256, 0, stream>>>(cayB, thetaT);
    enc_kernel<<<N_NODES, 64, 0, stream>>>(x, encW, encb, b);

    const int EW_BLOCKS = (NM / 4 + 255) / 256;   // 625

    auto run_g = [&](const float* uin, float* Fout) {
        tmap_kernel<<<EW_BLOCKS, 256, 0, stream>>>(uin, b, t);
        hipMemsetAsync(S, 0, NM * sizeof(float), stream);
        spmm_kernel<<<4096, 256, 0, stream>>>(src, dst, ew, t, S);
        apply_kernel<<<N_NODES / 4, 256, 0, stream>>>(S, b, thetaT, Fout);
    };

    // init phase: X[i] = u_i, F[i] = g(u_i);  u_0 = b, u_{i+1} = F[i]
    for (int i = 0; i < 5; i++) {
        const float* ui = (i == 0) ? b : (Fb + (i - 1) * NM);
        hipMemcpyAsync(Xb + i * NM, ui, NM * sizeof(float),
                       hipMemcpyDeviceToDevice, stream);
        run_g(Xb + i * NM, Fb + i * NM);
    }

    // Anderson phase (5 steps; slot k); last g(u_new) is dead -> skipped
    for (int k = 0; k < 5; k++) {
        hipMemsetAsync(GG, 0, 15 * sizeof(double), stream);
        gg_kernel<<<1024, 256, 0, stream>>>(Xb, Fb, GG);
        solve_kernel<<<1, 64, 0, stream>>>(GG, avec);
        combine_kernel<<<EW_BLOCKS, 256, 0, stream>>>(Fb, avec, Xb + k * NM);
        if (k < 4) run_g(Xb + k * NM, Fb + k * NM);
    }

    out_kernel<<<N_NODES / 16, 256, 0, stream>>>(Xb + 4 * NM, decW, out);
}

// Round 5
// 750.455 us; speedup vs baseline: 7.2912x; 7.2912x over previous
//
#include <hip/hip_runtime.h>
#include <math.h>

#define N_NODES 10000
#define N_EDGES 320000
#define D 64
#define D_IN 128
#define D_OUT 16
#define NM (N_NODES * D)   // 640000 elements per state vector
#define GG_BLOCKS 256

// ---------------------------------------------------------------------------
// Theta = (I + Om)^-1 (I - Om), Om = 0.5*(B - B^T).  One block, Gauss-Jordan
// with partial pivoting on the [64 x 128] augmented matrix in LDS.
// Stores Theta TRANSPOSED: thetaT[k*64 + d] = Theta[d][k].
// ---------------------------------------------------------------------------
__global__ void theta_kernel(const float* __restrict__ B, float* __restrict__ thetaT) {
    __shared__ float M[64][129];
    __shared__ float fcol[64];
    __shared__ int   piv_s;
    __shared__ float inv_s;
    const int tid = threadIdx.x;

    for (int i = tid; i < 64 * 128; i += 256) {
        int r = i >> 7, c = i & 127;
        float v;
        if (c < 64) {
            float om = 0.5f * (B[r * 64 + c] - B[c * 64 + r]);
            v = om + (r == c ? 1.0f : 0.0f);
        } else {
            int c2 = c - 64;
            float om = 0.5f * (B[r * 64 + c2] - B[c2 * 64 + r]);
            v = -om + (r == c2 ? 1.0f : 0.0f);
        }
        M[r][c] = v;
    }
    __syncthreads();

    for (int k = 0; k < 64; k++) {
        if (tid == 0) {
            int p = k; float best = fabsf(M[k][k]);
            for (int r = k + 1; r < 64; r++) {
                float v = fabsf(M[r][k]);
                if (v > best) { best = v; p = r; }
            }
            piv_s = p;
        }
        __syncthreads();
        int p = piv_s;
        if (p != k) {
            for (int c = tid; c < 128; c += 256) {
                float tmp = M[k][c]; M[k][c] = M[p][c]; M[p][c] = tmp;
            }
        }
        __syncthreads();
        if (tid == 0) inv_s = 1.0f / M[k][k];
        __syncthreads();
        float invp = inv_s;
        for (int c = tid; c < 128; c += 256) M[k][c] *= invp;
        __syncthreads();
        for (int r = tid; r < 64; r += 256) fcol[r] = M[r][k];
        __syncthreads();
        for (int i = tid; i < 64 * 128; i += 256) {
            int r = i >> 7, c = i & 127;
            if (r != k) M[r][c] -= fcol[r] * M[k][c];
        }
        __syncthreads();
    }
    for (int i = tid; i < 64 * 64; i += 256) {
        int kk = i >> 6, d = i & 63;
        thetaT[i] = M[d][64 + kk];
    }
}

// ---------------------------------------------------------------------------
// b = x @ enc_W + enc_b;  dual-writes X[0] = b and t0 = |b| + b.
// ---------------------------------------------------------------------------
__global__ void enc_kernel(const float* __restrict__ x, const float* __restrict__ W,
                           const float* __restrict__ bias, float* __restrict__ b,
                           float* __restrict__ x0, float* __restrict__ t0) {
    __shared__ float xrow[D_IN];
    const int node = blockIdx.x, tid = threadIdx.x;   // 64 threads
    xrow[tid]      = x[node * D_IN + tid];
    xrow[tid + 64] = x[node * D_IN + tid + 64];
    __syncthreads();
    float acc = bias[tid];
#pragma unroll
    for (int k = 0; k < D_IN; k++) acc = fmaf(xrow[k], W[k * D + tid], acc);
    b[node * D + tid]  = acc;
    x0[node * D + tid] = acc;
    t0[node * D + tid] = fabsf(acc) + acc;
}

// ---------------------------------------------------------------------------
// CSR build: count incoming edges per dst, exclusive scan, scatter (src,w).
// Rebuilt every launch (ws is re-poisoned); same work each call.
// ---------------------------------------------------------------------------
__global__ void count_kernel(const int* __restrict__ dst, int* __restrict__ counts) {
    int e = blockIdx.x * blockDim.x + threadIdx.x;
    const int stride = gridDim.x * blockDim.x;
    for (; e < N_EDGES; e += stride) atomicAdd(&counts[dst[e]], 1);
}

__global__ void scan_kernel(const int* __restrict__ counts, int* __restrict__ rowptr,
                            int* __restrict__ cursor) {
    __shared__ int buf[256];
    __shared__ int carry_s;
    const int tid = threadIdx.x;
    if (tid == 0) carry_s = 0;
    __syncthreads();
    for (int base = 0; base < N_NODES; base += 256) {
        int idx = base + tid;
        int v = (idx < N_NODES) ? counts[idx] : 0;
        buf[tid] = v;
        __syncthreads();
        for (int off = 1; off < 256; off <<= 1) {
            int x = (tid >= off) ? buf[tid - off] : 0;
            __syncthreads();
            buf[tid] += x;
            __syncthreads();
        }
        int incl = buf[tid];
        int excl = incl - v;
        if (idx < N_NODES) {
            rowptr[idx] = carry_s + excl;
            cursor[idx] = carry_s + excl;
        }
        __syncthreads();
        if (tid == 255) carry_s += incl;
        __syncthreads();
    }
    if (tid == 0) rowptr[N_NODES] = carry_s;   // == N_EDGES
}

__global__ void scatter_kernel(const int* __restrict__ src, const int* __restrict__ dst,
                               const float* __restrict__ ew, int* __restrict__ cursor,
                               uint2* __restrict__ edata) {
    int e = blockIdx.x * blockDim.x + threadIdx.x;
    const int stride = gridDim.x * blockDim.x;
    for (; e < N_EDGES; e += stride) {
        int p = atomicAdd(&cursor[dst[e]], 1);
        edata[p] = make_uint2((unsigned)src[e], __float_as_uint(ew[e]));
    }
}

// ---------------------------------------------------------------------------
// Fused g: F[node] = b + 0.5 * Theta @ (A t_in)[node]   (one wave per node)
// CSR gather (no atomics), S-row in registers, Theta^T matvec via LDS.
// Optional dual-writes: Xnext = F (init history), t_out = |F| + b (next t).
// ---------------------------------------------------------------------------
__global__ void __launch_bounds__(256) g_kernel(
    const int* __restrict__ rowptr, const uint2* __restrict__ edata,
    const float* __restrict__ t_in, const float* __restrict__ b,
    const float* __restrict__ thetaT, float* __restrict__ F,
    float* __restrict__ Xnext, float* __restrict__ t_out) {
    __shared__ float Th[D * D];
    __shared__ float Srow[4][D];
    const int tid = threadIdx.x;
    for (int i = tid; i < D * D; i += 256) Th[i] = thetaT[i];
    const int ln = tid & 63, wv = tid >> 6;
    const int node = blockIdx.x * 4 + wv;
    __syncthreads();

    float acc = 0.0f;
    int e = rowptr[node];
    const int end = rowptr[node + 1];
    for (; e + 3 < end; e += 4) {           // unroll-4: 4 independent t-row loads in flight
        uint2 a0 = edata[e], a1 = edata[e + 1], a2 = edata[e + 2], a3 = edata[e + 3];
        float v0 = t_in[a0.x * D + ln];
        float v1 = t_in[a1.x * D + ln];
        float v2 = t_in[a2.x * D + ln];
        float v3 = t_in[a3.x * D + ln];
        acc = fmaf(__uint_as_float(a0.y), v0, acc);
        acc = fmaf(__uint_as_float(a1.y), v1, acc);
        acc = fmaf(__uint_as_float(a2.y), v2, acc);
        acc = fmaf(__uint_as_float(a3.y), v3, acc);
    }
    for (; e < end; ++e) {
        uint2 a = edata[e];
        acc = fmaf(__uint_as_float(a.y), t_in[a.x * D + ln], acc);
    }
    Srow[wv][ln] = acc;
    __syncthreads();

    float r = 0.0f;
#pragma unroll
    for (int k = 0; k < D; k++) r = fmaf(Srow[wv][k], Th[k * D + ln], r);
    const float bb = b[node * D + ln];
    const float v = bb + 0.5f * r;
    F[node * D + ln] = v;
    if (Xnext) Xnext[node * D + ln] = v;
    if (t_out) t_out[node * D + ln] = fabsf(v) + bb;
}

// ---------------------------------------------------------------------------
// Anderson: per-block partials of the GG upper triangle (15 entries) in f64.
// No global atomics: block -> GGpart[blk*16 + p].
// ---------------------------------------------------------------------------
__global__ void gg_kernel(const float* __restrict__ Xb, const float* __restrict__ Fb,
                          double* __restrict__ GGpart) {
    __shared__ double swave[4][16];
    double acc[15];
#pragma unroll
    for (int p = 0; p < 15; p++) acc[p] = 0.0;
    int idx = blockIdx.x * blockDim.x + threadIdx.x;
    const int stride = gridDim.x * blockDim.x;
    for (int i = idx; i < NM; i += stride) {
        float g[5];
#pragma unroll
        for (int j = 0; j < 5; j++) g[j] = Fb[j * NM + i] - Xb[j * NM + i];
        int p = 0;
#pragma unroll
        for (int a = 0; a < 5; a++)
#pragma unroll
            for (int bq = a; bq < 5; bq++) acc[p++] += (double)g[a] * (double)g[bq];
    }
#pragma unroll
    for (int p = 0; p < 15; p++)
        for (int o = 32; o > 0; o >>= 1) acc[p] += __shfl_down(acc[p], o, 64);
    const int wv = threadIdx.x >> 6;
    if ((threadIdx.x & 63) == 0) {
#pragma unroll
        for (int p = 0; p < 15; p++) swave[wv][p] = acc[p];
    }
    __syncthreads();
    if (threadIdx.x < 15) {
        double s = swave[0][threadIdx.x] + swave[1][threadIdx.x] +
                   swave[2][threadIdx.x] + swave[3][threadIdx.x];
        GGpart[blockIdx.x * 16 + threadIdx.x] = s;
    }
}

// ---------------------------------------------------------------------------
// Sum GGpart (16 lanes per entry), then a = (GG + lam I)^-1 1; a /= sum(a).
// ---------------------------------------------------------------------------
__global__ void solve_kernel(const double* __restrict__ GGpart, float* __restrict__ a) {
    __shared__ double GG[16];
    const int tid = threadIdx.x;
    const int p = tid >> 4;
    const int g = tid & 15;
    double s = 0.0;
    if (p < 15) {
        for (int blk = g; blk < GG_BLOCKS; blk += 16) s += GGpart[blk * 16 + p];
    }
#pragma unroll
    for (int o = 8; o > 0; o >>= 1) s += __shfl_down(s, o, 16);
    if (g == 0 && p < 15) GG[p] = s;
    __syncthreads();
    if (tid != 0) return;
    double A[5][5], rhs[5];
    int q = 0;
    for (int r = 0; r < 5; r++)
        for (int c = r; c < 5; c++) { double v = GG[q++]; A[r][c] = v; A[c][r] = v; }
    for (int i = 0; i < 5; i++) { A[i][i] += 1e-4; rhs[i] = 1.0; }
    for (int i = 0; i < 5; i++) {
        int piv = i; double best = fabs(A[i][i]);
        for (int r = i + 1; r < 5; r++) {
            double v = fabs(A[r][i]);
            if (v > best) { best = v; piv = r; }
        }
        if (piv != i) {
            for (int c = 0; c < 5; c++) { double tmp = A[i][c]; A[i][c] = A[piv][c]; A[piv][c] = tmp; }
            double tr = rhs[i]; rhs[i] = rhs[piv]; rhs[piv] = tr;
        }
        double inv = 1.0 / A[i][i];
        for (int c = 0; c < 5; c++) A[i][c] *= inv;
        rhs[i] *= inv;
        for (int r = 0; r < 5; r++)
            if (r != i) {
                double f = A[r][i];
                for (int c = 0; c < 5; c++) A[r][c] -= f * A[i][c];
                rhs[r] -= f * rhs[i];
            }
    }
    double ssum = rhs[0] + rhs[1] + rhs[2] + rhs[3] + rhs[4];
    for (int j = 0; j < 5; j++) a[j] = (float)(rhs[j] / ssum);
}

// ---------------------------------------------------------------------------
// Xk = sum_j a[j] * F[j];  fused t = |Xk| + b for the following g.
// ---------------------------------------------------------------------------
__global__ void combine_kernel(const float* __restrict__ Fb, const float* __restrict__ a,
                               const float* __restrict__ b, float* __restrict__ Xk,
                               float* __restrict__ t) {
    __shared__ float as[5];
    if (threadIdx.x < 5) as[threadIdx.x] = a[threadIdx.x];
    __syncthreads();
    int i = blockIdx.x * blockDim.x + threadIdx.x;
    if (i >= NM / 4) return;
    float4 r = {0.f, 0.f, 0.f, 0.f};
#pragma unroll
    for (int j = 0; j < 5; j++) {
        const float4 f = ((const float4*)(Fb + j * NM))[i];
        float aj = as[j];
        r.x = fmaf(aj, f.x, r.x);
        r.y = fmaf(aj, f.y, r.y);
        r.z = fmaf(aj, f.z, r.z);
        r.w = fmaf(aj, f.w, r.w);
    }
    ((float4*)Xk)[i] = r;
    const float4 bv = ((const float4*)b)[i];
    float4 tv;
    tv.x = fabsf(r.x) + bv.x;
    tv.y = fabsf(r.y) + bv.y;
    tv.z = fabsf(r.z) + bv.z;
    tv.w = fabsf(r.w) + bv.w;
    ((float4*)t)[i] = tv;
}

// ---------------------------------------------------------------------------
// out[node][o] = sum_d relu(u[node][d]) * decW[d][o]
// ---------------------------------------------------------------------------
__global__ void out_kernel(const float* __restrict__ u, const float* __restrict__ decW,
                           float* __restrict__ out) {
    __shared__ float W[D * D_OUT];
    __shared__ float rows[16][D + 1];
    const int tid = threadIdx.x;
    for (int i = tid; i < D * D_OUT; i += 256) W[i] = decW[i];
    const int node0 = blockIdx.x * 16;
    for (int i = tid; i < 16 * D; i += 256) {
        int n = i >> 6, d = i & 63;
        rows[n][d] = u[(node0 + n) * D + d];
    }
    __syncthreads();
    const int n = tid >> 4, o = tid & 15;
    float acc = 0.0f;
#pragma unroll
    for (int d2 = 0; d2 < D; d2++)
        acc = fmaf(fmaxf(rows[n][d2], 0.0f), W[d2 * D_OUT + o], acc);
    out[(node0 + n) * D_OUT + o] = acc;
}

// ---------------------------------------------------------------------------
extern "C" void kernel_launch(void* const* d_in, const int* in_sizes, int n_in,
                              void* d_out, int out_size, void* d_ws, size_t ws_size,
                              hipStream_t stream) {
    const float* x    = (const float*)d_in[0];
    const int*   ei   = (const int*)d_in[1];
    const float* ew   = (const float*)d_in[2];
    const float* encW = (const float*)d_in[3];
    const float* encb = (const float*)d_in[4];
    const float* cayB = (const float*)d_in[5];
    const float* decW = (const float*)d_in[6];
    float* out = (float*)d_out;
    const int* src = ei;
    const int* dst = ei + N_EDGES;

    char* w = (char*)d_ws;
    double* GGpart = (double*)w;                       // 32768 B
    float*  avec   = (float*)(w + 32768);              // 256 B reserved
    float*  thetaT = (float*)(w + 33024);              // 16384 B
    int*    counts = (int*)(w + 49408);                // 40000 B
    int*    rowptr = (int*)(w + 89408);                // 40004 B -> pad to 40192
    int*    cursor = (int*)(w + 129600);               // 40000 B -> pad to 40384
    uint2*  edata  = (uint2*)(w + 169984);             // 2560000 B
    float*  b   = (float*)(w + 2729984);
    float*  t0  = b + NM;
    float*  t1  = t0 + NM;
    float*  Xb  = t1 + NM;                             // 5 slots
    float*  Fb  = Xb + 5 * NM;                         // 5 slots

    theta_kernel<<<1, 256, 0, stream>>>(cayB, thetaT);
    enc_kernel<<<N_NODES, 64, 0, stream>>>(x, encW, encb, b, Xb, t0); // X[0]=b, t0=|b|+b

    // CSR build (dst-sorted)
    hipMemsetAsync(counts, 0, N_NODES * sizeof(int), stream);
    count_kernel<<<512, 256, 0, stream>>>(dst, counts);
    scan_kernel<<<1, 256, 0, stream>>>(counts, rowptr, cursor);
    scatter_kernel<<<512, 256, 0, stream>>>(src, dst, ew, cursor, edata);

    const int EW_BLOCKS = (NM / 4 + 255) / 256;   // 625

    // init phase: F[i] = g(X[i]); X[i+1] = F[i]; t ping-pong (g_i reads t_{i%2})
    for (int i = 0; i < 5; i++) {
        float* tin  = (i & 1) ? t1 : t0;
        float* tout = (i < 4) ? ((i & 1) ? t0 : t1) : nullptr;
        g_kernel<<<N_NODES / 4, 256, 0, stream>>>(
            rowptr, edata, tin, b, thetaT, Fb + i * NM,
            (i < 4) ? (Xb + (i + 1) * NM) : nullptr, tout);
    }

    // Anderson phase: combine writes X[k] and t0; g reads t0 (no t_out needed)
    for (int k = 0; k < 5; k++) {
        gg_kernel<<<GG_BLOCKS, 256, 0, stream>>>(Xb, Fb, GGpart);
        solve_kernel<<<1, 256, 0, stream>>>(GGpart, avec);
        combine_kernel<<<EW_BLOCKS, 256, 0, stream>>>(Fb, avec, b, Xb + k * NM, t0);
        if (k < 4)
            g_kernel<<<N_NODES / 4, 256, 0, stream>>>(
                rowptr, edata, t0, b, thetaT, Fb + k * NM, nullptr, nullptr);
    }

    out_kernel<<<N_NODES / 16, 256, 0, stream>>>(Xb + 4 * NM, decW, out);
}

// Round 6
// 612.116 us; speedup vs baseline: 8.9390x; 1.2260x over previous
//
#include <hip/hip_runtime.h>
#include <math.h>

#define N_NODES 10000
#define N_EDGES 320000
#define D 64
#define D_IN 128
#define D_OUT 16
#define NM (N_NODES * D)   // 640000 elements per state vector
#define GG_BLOCKS 256

// ---------------------------------------------------------------------------
// Theta = (I + Om)^-1 (I - Om), Om = 0.5*(B - B^T).  One block, Gauss-Jordan
// WITHOUT pivoting: for A = I + Om (Om skew), every Schur-complement pivot
// is provably >= 1 (sym part stays ⪰ I), so no search/swap is needed.
// 2 barriers per iteration; column k is never written during iteration k so
// the multiplier read M[r][k] is race-free.
// Stores Theta TRANSPOSED: thetaT[k*64 + d] = Theta[d][k].
// ---------------------------------------------------------------------------
__global__ void theta_kernel(const float* __restrict__ B, float* __restrict__ thetaT) {
    __shared__ float M[64][129];
    const int tid = threadIdx.x;

    for (int i = tid; i < 64 * 128; i += 256) {
        int r = i >> 7, c = i & 127;
        float v;
        if (c < 64) {
            float om = 0.5f * (B[r * 64 + c] - B[c * 64 + r]);
            v = om + (r == c ? 1.0f : 0.0f);
        } else {
            int c2 = c - 64;
            float om = 0.5f * (B[r * 64 + c2] - B[c2 * 64 + r]);
            v = -om + (r == c2 ? 1.0f : 0.0f);
        }
        M[r][c] = v;
    }

    const int r  = tid & 63;        // row owned in the update step
    const int c0 = (tid >> 6) * 32; // 32-col chunk owned in the update step

    for (int k = 0; k < 64; k++) {
        __syncthreads();
        // scale row k: cols != k (col k untouched -> pivot value stays readable;
        // every reader sees the same unwritten M[k][k], no race). Dead cols <k
        // get scaled too - harmless, never read again.
        if (tid < 128 && tid != k) M[k][tid] /= M[k][k];
        __syncthreads();
        // eliminate: rows r != k, cols c > k only (right half always c>=64>k).
        // Column k is skipped -> f = M[r][k] is stable during this phase.
        if (r != k) {
            const float f = M[r][k];
#pragma unroll
            for (int j = 0; j < 32; j++) {
                const int c = c0 + j;
                if (c > k) M[r][c] = fmaf(-f, M[k][c], M[r][c]);
            }
        }
    }
    __syncthreads();
    // right half is Theta; store transposed
    for (int i = tid; i < 64 * 64; i += 256) {
        int kk = i >> 6, d = i & 63;
        thetaT[i] = M[d][64 + kk];
    }
}

// ---------------------------------------------------------------------------
// b = x @ enc_W + enc_b;  dual-writes X[0] = b and t0 = |b| + b.
// ---------------------------------------------------------------------------
__global__ void enc_kernel(const float* __restrict__ x, const float* __restrict__ W,
                           const float* __restrict__ bias, float* __restrict__ b,
                           float* __restrict__ x0, float* __restrict__ t0) {
    __shared__ float xrow[D_IN];
    const int node = blockIdx.x, tid = threadIdx.x;   // 64 threads
    xrow[tid]      = x[node * D_IN + tid];
    xrow[tid + 64] = x[node * D_IN + tid + 64];
    __syncthreads();
    float acc = bias[tid];
#pragma unroll
    for (int k = 0; k < D_IN; k++) acc = fmaf(xrow[k], W[k * D + tid], acc);
    b[node * D + tid]  = acc;
    x0[node * D + tid] = acc;
    t0[node * D + tid] = fabsf(acc) + acc;
}

// ---------------------------------------------------------------------------
// CSR build: count incoming edges per dst, exclusive scan, scatter (src,w).
// Rebuilt every launch (ws is re-poisoned); same work each call.
// ---------------------------------------------------------------------------
__global__ void count_kernel(const int* __restrict__ dst, int* __restrict__ counts) {
    int e = blockIdx.x * blockDim.x + threadIdx.x;
    const int stride = gridDim.x * blockDim.x;
    for (; e < N_EDGES; e += stride) atomicAdd(&counts[dst[e]], 1);
}

__global__ void scan_kernel(const int* __restrict__ counts, int* __restrict__ rowptr,
                            int* __restrict__ cursor) {
    __shared__ int buf[256];
    __shared__ int carry_s;
    const int tid = threadIdx.x;
    if (tid == 0) carry_s = 0;
    __syncthreads();
    for (int base = 0; base < N_NODES; base += 256) {
        int idx = base + tid;
        int v = (idx < N_NODES) ? counts[idx] : 0;
        buf[tid] = v;
        __syncthreads();
        for (int off = 1; off < 256; off <<= 1) {
            int x = (tid >= off) ? buf[tid - off] : 0;
            __syncthreads();
            buf[tid] += x;
            __syncthreads();
        }
        int incl = buf[tid];
        int excl = incl - v;
        if (idx < N_NODES) {
            rowptr[idx] = carry_s + excl;
            cursor[idx] = carry_s + excl;
        }
        __syncthreads();
        if (tid == 255) carry_s += incl;
        __syncthreads();
    }
    if (tid == 0) rowptr[N_NODES] = carry_s;   // == N_EDGES
}

__global__ void scatter_kernel(const int* __restrict__ src, const int* __restrict__ dst,
                               const float* __restrict__ ew, int* __restrict__ cursor,
                               uint2* __restrict__ edata) {
    int e = blockIdx.x * blockDim.x + threadIdx.x;
    const int stride = gridDim.x * blockDim.x;
    for (; e < N_EDGES; e += stride) {
        int p = atomicAdd(&cursor[dst[e]], 1);
        edata[p] = make_uint2((unsigned)src[e], __float_as_uint(ew[e]));
    }
}

// ---------------------------------------------------------------------------
// Fused g: F[node] = b + 0.5 * Theta @ (A t_in)[node]   (one wave per node)
// CSR gather (no atomics), S-row in registers, Theta^T matvec via LDS.
// Optional dual-writes: Xnext = F (init history), t_out = |F| + b (next t).
// ---------------------------------------------------------------------------
__global__ void __launch_bounds__(256) g_kernel(
    const int* __restrict__ rowptr, const uint2* __restrict__ edata,
    const float* __restrict__ t_in, const float* __restrict__ b,
    const float* __restrict__ thetaT, float* __restrict__ F,
    float* __restrict__ Xnext, float* __restrict__ t_out) {
    __shared__ float Th[D * D];
    __shared__ float Srow[4][D];
    const int tid = threadIdx.x;
    for (int i = tid; i < D * D; i += 256) Th[i] = thetaT[i];
    const int ln = tid & 63, wv = tid >> 6;
    const int node = blockIdx.x * 4 + wv;
    __syncthreads();

    float acc = 0.0f;
    int e = rowptr[node];
    const int end = rowptr[node + 1];
    for (; e + 3 < end; e += 4) {           // unroll-4: 4 independent t-row loads in flight
        uint2 a0 = edata[e], a1 = edata[e + 1], a2 = edata[e + 2], a3 = edata[e + 3];
        float v0 = t_in[a0.x * D + ln];
        float v1 = t_in[a1.x * D + ln];
        float v2 = t_in[a2.x * D + ln];
        float v3 = t_in[a3.x * D + ln];
        acc = fmaf(__uint_as_float(a0.y), v0, acc);
        acc = fmaf(__uint_as_float(a1.y), v1, acc);
        acc = fmaf(__uint_as_float(a2.y), v2, acc);
        acc = fmaf(__uint_as_float(a3.y), v3, acc);
    }
    for (; e < end; ++e) {
        uint2 a = edata[e];
        acc = fmaf(__uint_as_float(a.y), t_in[a.x * D + ln], acc);
    }
    Srow[wv][ln] = acc;
    __syncthreads();

    float r = 0.0f;
#pragma unroll
    for (int k = 0; k < D; k++) r = fmaf(Srow[wv][k], Th[k * D + ln], r);
    const float bb = b[node * D + ln];
    const float v = bb + 0.5f * r;
    F[node * D + ln] = v;
    if (Xnext) Xnext[node * D + ln] = v;
    if (t_out) t_out[node * D + ln] = fabsf(v) + bb;
}

// ---------------------------------------------------------------------------
// Anderson: per-block partials of the GG upper triangle (15 entries) in f64.
// No global atomics: block -> GGpart[blk*16 + p].
// ---------------------------------------------------------------------------
__global__ void gg_kernel(const float* __restrict__ Xb, const float* __restrict__ Fb,
                          double* __restrict__ GGpart) {
    __shared__ double swave[4][16];
    double acc[15];
#pragma unroll
    for (int p = 0; p < 15; p++) acc[p] = 0.0;
    int idx = blockIdx.x * blockDim.x + threadIdx.x;
    const int stride = gridDim.x * blockDim.x;
    for (int i = idx; i < NM; i += stride) {
        float g[5];
#pragma unroll
        for (int j = 0; j < 5; j++) g[j] = Fb[j * NM + i] - Xb[j * NM + i];
        int p = 0;
#pragma unroll
        for (int a = 0; a < 5; a++)
#pragma unroll
            for (int bq = a; bq < 5; bq++) acc[p++] += (double)g[a] * (double)g[bq];
    }
#pragma unroll
    for (int p = 0; p < 15; p++)
        for (int o = 32; o > 0; o >>= 1) acc[p] += __shfl_down(acc[p], o, 64);
    const int wv = threadIdx.x >> 6;
    if ((threadIdx.x & 63) == 0) {
#pragma unroll
        for (int p = 0; p < 15; p++) swave[wv][p] = acc[p];
    }
    __syncthreads();
    if (threadIdx.x < 15) {
        double s = swave[0][threadIdx.x] + swave[1][threadIdx.x] +
                   swave[2][threadIdx.x] + swave[3][threadIdx.x];
        GGpart[blockIdx.x * 16 + threadIdx.x] = s;
    }
}

// ---------------------------------------------------------------------------
// Sum GGpart (16 lanes per entry), then a = (GG + lam I)^-1 1; a /= sum(a).
// ---------------------------------------------------------------------------
__global__ void solve_kernel(const double* __restrict__ GGpart, float* __restrict__ a) {
    __shared__ double GG[16];
    const int tid = threadIdx.x;
    const int p = tid >> 4;
    const int g = tid & 15;
    double s = 0.0;
    if (p < 15) {
        for (int blk = g; blk < GG_BLOCKS; blk += 16) s += GGpart[blk * 16 + p];
    }
#pragma unroll
    for (int o = 8; o > 0; o >>= 1) s += __shfl_down(s, o, 16);
    if (g == 0 && p < 15) GG[p] = s;
    __syncthreads();
    if (tid != 0) return;
    double A[5][5], rhs[5];
    int q = 0;
    for (int r = 0; r < 5; r++)
        for (int c = r; c < 5; c++) { double v = GG[q++]; A[r][c] = v; A[c][r] = v; }
    for (int i = 0; i < 5; i++) { A[i][i] += 1e-4; rhs[i] = 1.0; }
    for (int i = 0; i < 5; i++) {
        int piv = i; double best = fabs(A[i][i]);
        for (int r = i + 1; r < 5; r++) {
            double v = fabs(A[r][i]);
            if (v > best) { best = v; piv = r; }
        }
        if (piv != i) {
            for (int c = 0; c < 5; c++) { double tmp = A[i][c]; A[i][c] = A[piv][c]; A[piv][c] = tmp; }
            double tr = rhs[i]; rhs[i] = rhs[piv]; rhs[piv] = tr;
        }
        double inv = 1.0 / A[i][i];
        for (int c = 0; c < 5; c++) A[i][c] *= inv;
        rhs[i] *= inv;
        for (int r = 0; r < 5; r++)
            if (r != i) {
                double f = A[r][i];
                for (int c = 0; c < 5; c++) A[r][c] -= f * A[i][c];
                rhs[r] -= f * rhs[i];
            }
    }
    double ssum = rhs[0] + rhs[1] + rhs[2] + rhs[3] + rhs[4];
    for (int j = 0; j < 5; j++) a[j] = (float)(rhs[j] / ssum);
}

// ---------------------------------------------------------------------------
// Xk = sum_j a[j] * F[j];  fused t = |Xk| + b for the following g.
// ---------------------------------------------------------------------------
__global__ void combine_kernel(const float* __restrict__ Fb, const float* __restrict__ a,
                               const float* __restrict__ b, float* __restrict__ Xk,
                               float* __restrict__ t) {
    __shared__ float as[5];
    if (threadIdx.x < 5) as[threadIdx.x] = a[threadIdx.x];
    __syncthreads();
    int i = blockIdx.x * blockDim.x + threadIdx.x;
    if (i >= NM / 4) return;
    float4 r = {0.f, 0.f, 0.f, 0.f};
#pragma unroll
    for (int j = 0; j < 5; j++) {
        const float4 f = ((const float4*)(Fb + j * NM))[i];
        float aj = as[j];
        r.x = fmaf(aj, f.x, r.x);
        r.y = fmaf(aj, f.y, r.y);
        r.z = fmaf(aj, f.z, r.z);
        r.w = fmaf(aj, f.w, r.w);
    }
    ((float4*)Xk)[i] = r;
    const float4 bv = ((const float4*)b)[i];
    float4 tv;
    tv.x = fabsf(r.x) + bv.x;
    tv.y = fabsf(r.y) + bv.y;
    tv.z = fabsf(r.z) + bv.z;
    tv.w = fabsf(r.w) + bv.w;
    ((float4*)t)[i] = tv;
}

// ---------------------------------------------------------------------------
// out[node][o] = sum_d relu(u[node][d]) * decW[d][o]
// ---------------------------------------------------------------------------
__global__ void out_kernel(const float* __restrict__ u, const float* __restrict__ decW,
                           float* __restrict__ out) {
    __shared__ float W[D * D_OUT];
    __shared__ float rows[16][D + 1];
    const int tid = threadIdx.x;
    for (int i = tid; i < D * D_OUT; i += 256) W[i] = decW[i];
    const int node0 = blockIdx.x * 16;
    for (int i = tid; i < 16 * D; i += 256) {
        int n = i >> 6, d = i & 63;
        rows[n][d] = u[(node0 + n) * D + d];
    }
    __syncthreads();
    const int n = tid >> 4, o = tid & 15;
    float acc = 0.0f;
#pragma unroll
    for (int d2 = 0; d2 < D; d2++)
        acc = fmaf(fmaxf(rows[n][d2], 0.0f), W[d2 * D_OUT + o], acc);
    out[(node0 + n) * D_OUT + o] = acc;
}

// ---------------------------------------------------------------------------
extern "C" void kernel_launch(void* const* d_in, const int* in_sizes, int n_in,
                              void* d_out, int out_size, void* d_ws, size_t ws_size,
                              hipStream_t stream) {
    const float* x    = (const float*)d_in[0];
    const int*   ei   = (const int*)d_in[1];
    const float* ew   = (const float*)d_in[2];
    const float* encW = (const float*)d_in[3];
    const float* encb = (const float*)d_in[4];
    const float* cayB = (const float*)d_in[5];
    const float* decW = (const float*)d_in[6];
    float* out = (float*)d_out;
    const int* src = ei;
    const int* dst = ei + N_EDGES;

    char* w = (char*)d_ws;
    double* GGpart = (double*)w;                       // 32768 B
    float*  avec   = (float*)(w + 32768);              // 256 B reserved
    float*  thetaT = (float*)(w + 33024);              // 16384 B
    int*    counts = (int*)(w + 49408);                // 40000 B
    int*    rowptr = (int*)(w + 89408);                // 40004 B -> pad to 40192
    int*    cursor = (int*)(w + 129600);               // 40000 B -> pad to 40384
    uint2*  edata  = (uint2*)(w + 169984);             // 2560000 B
    float*  b   = (float*)(w + 2729984);
    float*  t0  = b + NM;
    float*  t1  = t0 + NM;
    float*  Xb  = t1 + NM;                             // 5 slots
    float*  Fb  = Xb + 5 * NM;                         // 5 slots

    theta_kernel<<<1, 256, 0, stream>>>(cayB, thetaT);
    enc_kernel<<<N_NODES, 64, 0, stream>>>(x, encW, encb, b, Xb, t0); // X[0]=b, t0=|b|+b

    // CSR build (dst-sorted)
    hipMemsetAsync(counts, 0, N_NODES * sizeof(int), stream);
    count_kernel<<<512, 256, 0, stream>>>(dst, counts);
    scan_kernel<<<1, 256, 0, stream>>>(counts, rowptr, cursor);
    scatter_kernel<<<512, 256, 0, stream>>>(src, dst, ew, cursor, edata);

    const int EW_BLOCKS = (NM / 4 + 255) / 256;   // 625

    // init phase: F[i] = g(X[i]); X[i+1] = F[i]; t ping-pong (g_i reads t_{i%2})
    for (int i = 0; i < 5; i++) {
        float* tin  = (i & 1) ? t1 : t0;
        float* tout = (i < 4) ? ((i & 1) ? t0 : t1) : nullptr;
        g_kernel<<<N_NODES / 4, 256, 0, stream>>>(
            rowptr, edata, tin, b, thetaT, Fb + i * NM,
            (i < 4) ? (Xb + (i + 1) * NM) : nullptr, tout);
    }

    // Anderson phase: combine writes X[k] and t0; g reads t0 (no t_out needed)
    for (int k = 0; k < 5; k++) {
        gg_kernel<<<GG_BLOCKS, 256, 0, stream>>>(Xb, Fb, GGpart);
        solve_kernel<<<1, 256, 0, stream>>>(GGpart, avec);
        combine_kernel<<<EW_BLOCKS, 256, 0, stream>>>(Fb, avec, b, Xb + k * NM, t0);
        if (k < 4)
            g_kernel<<<N_NODES / 4, 256, 0, stream>>>(
                rowptr, edata, t0, b, thetaT, Fb + k * NM, nullptr, nullptr);
    }

    out_kernel<<<N_NODES / 16, 256, 0, stream>>>(Xb + 4 * NM, decW, out);
}

// Round 7
// 490.944 us; speedup vs baseline: 11.1452x; 1.2468x over previous
//
#include <hip/hip_runtime.h>
#include <math.h>

#define N_NODES 10000
#define N_EDGES 320000
#define D 64
#define D_IN 128
#define D_OUT 16
#define NM (N_NODES * D)   // 640000 elements per state vector
#define GG_BLOCKS 256

// ---------------------------------------------------------------------------
// Fused setup: block 0 computes Theta = (I+Om)^-1 (I-Om) (no-pivot GJ, valid
// since sym part of every Schur complement stays >= I for A = I + skew);
// blocks 1..625 do enc (16 nodes each, one node per wave) + edge counting.
// All three parts are independent; block 0 dispatches first so theta's
// single-CU latency is hidden under the enc/count blocks.
// Theta stored TRANSPOSED: thetaT[k*64 + d] = Theta[d][k].
// ---------------------------------------------------------------------------
__global__ void __launch_bounds__(1024) setup_kernel(
    const float* __restrict__ B, float* __restrict__ thetaT,
    const float* __restrict__ x, const float* __restrict__ encW,
    const float* __restrict__ encb, float* __restrict__ b,
    float* __restrict__ x0, float* __restrict__ t0,
    const int* __restrict__ dst, int* __restrict__ counts) {
    __shared__ float sh[64 * 132];          // 33792 B; enc blocks reuse 8 KB of it
    const int tid = threadIdx.x;

    if (blockIdx.x == 0) {
        // ---------------- theta: 64x128 augmented [A | I-Om] ----------------
        for (int i = tid; i < 64 * 128; i += 1024) {
            int r = i >> 7, c = i & 127;
            float v;
            if (c < 64) {
                float om = 0.5f * (B[r * 64 + c] - B[c * 64 + r]);
                v = om + (r == c ? 1.0f : 0.0f);
            } else {
                int c2 = c - 64;
                float om = 0.5f * (B[r * 64 + c2] - B[c2 * 64 + r]);
                v = -om + (r == c2 ? 1.0f : 0.0f);
            }
            sh[r * 132 + c] = v;
        }
        const int r = tid >> 4;             // owned row (64)
        const int cbase = (tid & 15) * 8;   // owned 8-col chunk (16)
        for (int k = 0; k < 64; ++k) {
            __syncthreads();
            // scale row k, cols != k (col k never written -> pivot readable)
            if (tid < 128 && tid != k) sh[k * 132 + tid] /= sh[k * 132 + k];
            __syncthreads();
            // eliminate rows r != k, cols > k only (col k skipped -> f stable)
            if (r != k) {
                const float f = sh[r * 132 + k];
                if (cbase > k) {            // chunk fully beyond k: vector path
                    float4 a0 = *(const float4*)&sh[k * 132 + cbase];
                    float4 a1 = *(const float4*)&sh[k * 132 + cbase + 4];
                    float4 b0 = *(float4*)&sh[r * 132 + cbase];
                    float4 b1 = *(float4*)&sh[r * 132 + cbase + 4];
                    b0.x = fmaf(-f, a0.x, b0.x); b0.y = fmaf(-f, a0.y, b0.y);
                    b0.z = fmaf(-f, a0.z, b0.z); b0.w = fmaf(-f, a0.w, b0.w);
                    b1.x = fmaf(-f, a1.x, b1.x); b1.y = fmaf(-f, a1.y, b1.y);
                    b1.z = fmaf(-f, a1.z, b1.z); b1.w = fmaf(-f, a1.w, b1.w);
                    *(float4*)&sh[r * 132 + cbase] = b0;
                    *(float4*)&sh[r * 132 + cbase + 4] = b1;
                } else if (cbase + 7 > k) { // chunk straddles k: scalar predicated
#pragma unroll
                    for (int j = 0; j < 8; ++j) {
                        int c = cbase + j;
                        if (c > k) sh[r * 132 + c] = fmaf(-f, sh[k * 132 + c], sh[r * 132 + c]);
                    }
                }                           // chunk fully <= k: dead, skip
            }
        }
        __syncthreads();
        for (int i = tid; i < 64 * 64; i += 1024) {
            int kk = i >> 6, d = i & 63;
            thetaT[i] = sh[d * 132 + 64 + kk];
        }
    } else {
        // ---------------- enc: 16 nodes/block, one node per wave ------------
        const int node0 = (blockIdx.x - 1) * 16;
        sh[tid]        = x[node0 * D_IN + tid];
        sh[tid + 1024] = x[node0 * D_IN + 1024 + tid];
        __syncthreads();
        const int nl = tid >> 6, lane = tid & 63;
        const int node = node0 + nl;
        const float* xr = &sh[nl * D_IN];   // wave-uniform reads -> LDS broadcast
        float acc = encb[lane];
#pragma unroll
        for (int k = 0; k < D_IN; ++k) acc = fmaf(xr[k], encW[k * D + lane], acc);
        b[node * D + lane]  = acc;
        x0[node * D + lane] = acc;
        t0[node * D + lane] = fabsf(acc) + acc;
        // ---------------- count incoming edges ------------------------------
        int e = (blockIdx.x - 1) * 1024 + tid;
        const int stride = 625 * 1024;
        for (; e < N_EDGES; e += stride) atomicAdd(&counts[dst[e]], 1);
    }
}

// ---------------------------------------------------------------------------
// Exclusive scan of counts -> rowptr/cursor.  1024 threads x 10 serial each,
// shfl wave-scan + 16-wave LDS combine: 2 barriers total (was 640).
// ---------------------------------------------------------------------------
__global__ void __launch_bounds__(1024) scan_kernel(
    const int* __restrict__ counts, int* __restrict__ rowptr,
    int* __restrict__ cursor) {
    __shared__ int wtot[16];
    const int tid = threadIdx.x;
    const int base = tid * 10;
    int c[10];
    int T = 0;
#pragma unroll
    for (int j = 0; j < 10; ++j) {
        int idx = base + j;
        c[j] = (idx < N_NODES) ? counts[idx] : 0;
        T += c[j];
    }
    int incl = T;                            // wave-inclusive scan
#pragma unroll
    for (int o = 1; o < 64; o <<= 1) {
        int v = __shfl_up(incl, o, 64);
        if ((tid & 63) >= o) incl += v;
    }
    const int wv = tid >> 6;
    if ((tid & 63) == 63) wtot[wv] = incl;
    __syncthreads();
    int wpre = 0;
#pragma unroll
    for (int w2 = 0; w2 < 16; ++w2) wpre += (w2 < wv) ? wtot[w2] : 0;
    int run = wpre + (incl - T);             // global exclusive offset
#pragma unroll
    for (int j = 0; j < 10; ++j) {
        int idx = base + j;
        if (idx < N_NODES) { rowptr[idx] = run; cursor[idx] = run; }
        run += c[j];
    }
    if (tid == 1023) rowptr[N_NODES] = run;  // == N_EDGES
}

__global__ void scatter_kernel(const int* __restrict__ src, const int* __restrict__ dst,
                               const float* __restrict__ ew, int* __restrict__ cursor,
                               uint2* __restrict__ edata) {
    int e = blockIdx.x * blockDim.x + threadIdx.x;
    const int stride = gridDim.x * blockDim.x;
    for (; e < N_EDGES; e += stride) {
        int p = atomicAdd(&cursor[dst[e]], 1);
        edata[p] = make_uint2((unsigned)src[e], __float_as_uint(ew[e]));
    }
}

// ---------------------------------------------------------------------------
// Fused g: F[node] = b + 0.5 * Theta @ (A t_in)[node]   (one wave per node)
// CSR gather (no atomics), S-row in registers, Theta^T matvec via LDS.
// Optional dual-writes: Xnext = F (init history), t_out = |F| + b (next t).
// ---------------------------------------------------------------------------
__global__ void __launch_bounds__(256) g_kernel(
    const int* __restrict__ rowptr, const uint2* __restrict__ edata,
    const float* __restrict__ t_in, const float* __restrict__ b,
    const float* __restrict__ thetaT, float* __restrict__ F,
    float* __restrict__ Xnext, float* __restrict__ t_out) {
    __shared__ float Th[D * D];
    __shared__ float Srow[4][D];
    const int tid = threadIdx.x;
    for (int i = tid; i < D * D; i += 256) Th[i] = thetaT[i];
    const int ln = tid & 63, wv = tid >> 6;
    const int node = blockIdx.x * 4 + wv;
    __syncthreads();

    float acc = 0.0f;
    int e = rowptr[node];
    const int end = rowptr[node + 1];
    for (; e + 3 < end; e += 4) {           // unroll-4: 4 independent t-row loads in flight
        uint2 a0 = edata[e], a1 = edata[e + 1], a2 = edata[e + 2], a3 = edata[e + 3];
        float v0 = t_in[a0.x * D + ln];
        float v1 = t_in[a1.x * D + ln];
        float v2 = t_in[a2.x * D + ln];
        float v3 = t_in[a3.x * D + ln];
        acc = fmaf(__uint_as_float(a0.y), v0, acc);
        acc = fmaf(__uint_as_float(a1.y), v1, acc);
        acc = fmaf(__uint_as_float(a2.y), v2, acc);
        acc = fmaf(__uint_as_float(a3.y), v3, acc);
    }
    for (; e < end; ++e) {
        uint2 a = edata[e];
        acc = fmaf(__uint_as_float(a.y), t_in[a.x * D + ln], acc);
    }
    Srow[wv][ln] = acc;
    __syncthreads();

    float r = 0.0f;
#pragma unroll
    for (int k = 0; k < D; k++) r = fmaf(Srow[wv][k], Th[k * D + ln], r);
    const float bb = b[node * D + ln];
    const float v = bb + 0.5f * r;
    F[node * D + ln] = v;
    if (Xnext) Xnext[node * D + ln] = v;
    if (t_out) t_out[node * D + ln] = fabsf(v) + bb;
}

// ---------------------------------------------------------------------------
// Anderson: per-block partials of the GG upper triangle (15 entries) in f64.
// No global atomics: block -> GGpart[blk*16 + p].
// ---------------------------------------------------------------------------
__global__ void gg_kernel(const float* __restrict__ Xb, const float* __restrict__ Fb,
                          double* __restrict__ GGpart) {
    __shared__ double swave[4][16];
    double acc[15];
#pragma unroll
    for (int p = 0; p < 15; p++) acc[p] = 0.0;
    int idx = blockIdx.x * blockDim.x + threadIdx.x;
    const int stride = gridDim.x * blockDim.x;
    for (int i = idx; i < NM; i += stride) {
        float g[5];
#pragma unroll
        for (int j = 0; j < 5; j++) g[j] = Fb[j * NM + i] - Xb[j * NM + i];
        int p = 0;
#pragma unroll
        for (int a = 0; a < 5; a++)
#pragma unroll
            for (int bq = a; bq < 5; bq++) acc[p++] += (double)g[a] * (double)g[bq];
    }
#pragma unroll
    for (int p = 0; p < 15; p++)
        for (int o = 32; o > 0; o >>= 1) acc[p] += __shfl_down(acc[p], o, 64);
    const int wv = threadIdx.x >> 6;
    if ((threadIdx.x & 63) == 0) {
#pragma unroll
        for (int p = 0; p < 15; p++) swave[wv][p] = acc[p];
    }
    __syncthreads();
    if (threadIdx.x < 15) {
        double s = swave[0][threadIdx.x] + swave[1][threadIdx.x] +
                   swave[2][threadIdx.x] + swave[3][threadIdx.x];
        GGpart[blockIdx.x * 16 + threadIdx.x] = s;
    }
}

// ---------------------------------------------------------------------------
// Sum GGpart (16 lanes per entry), then a = (GG + lam I)^-1 1; a /= sum(a).
// ---------------------------------------------------------------------------
__global__ void solve_kernel(const double* __restrict__ GGpart, float* __restrict__ a) {
    __shared__ double GG[16];
    const int tid = threadIdx.x;
    const int p = tid >> 4;
    const int g = tid & 15;
    double s = 0.0;
    if (p < 15) {
        for (int blk = g; blk < GG_BLOCKS; blk += 16) s += GGpart[blk * 16 + p];
    }
#pragma unroll
    for (int o = 8; o > 0; o >>= 1) s += __shfl_down(s, o, 16);
    if (g == 0 && p < 15) GG[p] = s;
    __syncthreads();
    if (tid != 0) return;
    double A[5][5], rhs[5];
    int q = 0;
    for (int r = 0; r < 5; r++)
        for (int c = r; c < 5; c++) { double v = GG[q++]; A[r][c] = v; A[c][r] = v; }
    for (int i = 0; i < 5; i++) { A[i][i] += 1e-4; rhs[i] = 1.0; }
    for (int i = 0; i < 5; i++) {
        int piv = i; double best = fabs(A[i][i]);
        for (int r = i + 1; r < 5; r++) {
            double v = fabs(A[r][i]);
            if (v > best) { best = v; piv = r; }
        }
        if (piv != i) {
            for (int c = 0; c < 5; c++) { double tmp = A[i][c]; A[i][c] = A[piv][c]; A[piv][c] = tmp; }
            double tr = rhs[i]; rhs[i] = rhs[piv]; rhs[piv] = tr;
        }
        double inv = 1.0 / A[i][i];
        for (int c = 0; c < 5; c++) A[i][c] *= inv;
        rhs[i] *= inv;
        for (int r = 0; r < 5; r++)
            if (r != i) {
                double f = A[r][i];
                for (int c = 0; c < 5; c++) A[r][c] -= f * A[i][c];
                rhs[r] -= f * rhs[i];
            }
    }
    double ssum = rhs[0] + rhs[1] + rhs[2] + rhs[3] + rhs[4];
    for (int j = 0; j < 5; j++) a[j] = (float)(rhs[j] / ssum);
}

// ---------------------------------------------------------------------------
// Xk = sum_j a[j] * F[j];  fused t = |Xk| + b for the following g.
// ---------------------------------------------------------------------------
__global__ void combine_kernel(const float* __restrict__ Fb, const float* __restrict__ a,
                               const float* __restrict__ b, float* __restrict__ Xk,
                               float* __restrict__ t) {
    __shared__ float as[5];
    if (threadIdx.x < 5) as[threadIdx.x] = a[threadIdx.x];
    __syncthreads();
    int i = blockIdx.x * blockDim.x + threadIdx.x;
    if (i >= NM / 4) return;
    float4 r = {0.f, 0.f, 0.f, 0.f};
#pragma unroll
    for (int j = 0; j < 5; j++) {
        const float4 f = ((const float4*)(Fb + j * NM))[i];
        float aj = as[j];
        r.x = fmaf(aj, f.x, r.x);
        r.y = fmaf(aj, f.y, r.y);
        r.z = fmaf(aj, f.z, r.z);
        r.w = fmaf(aj, f.w, r.w);
    }
    ((float4*)Xk)[i] = r;
    const float4 bv = ((const float4*)b)[i];
    float4 tv;
    tv.x = fabsf(r.x) + bv.x;
    tv.y = fabsf(r.y) + bv.y;
    tv.z = fabsf(r.z) + bv.z;
    tv.w = fabsf(r.w) + bv.w;
    ((float4*)t)[i] = tv;
}

// ---------------------------------------------------------------------------
// out[node][o] = sum_d relu(u[node][d]) * decW[d][o]
// ---------------------------------------------------------------------------
__global__ void out_kernel(const float* __restrict__ u, const float* __restrict__ decW,
                           float* __restrict__ out) {
    __shared__ float W[D * D_OUT];
    __shared__ float rows[16][D + 1];
    const int tid = threadIdx.x;
    for (int i = tid; i < D * D_OUT; i += 256) W[i] = decW[i];
    const int node0 = blockIdx.x * 16;
    for (int i = tid; i < 16 * D; i += 256) {
        int n = i >> 6, d = i & 63;
        rows[n][d] = u[(node0 + n) * D + d];
    }
    __syncthreads();
    const int n = tid >> 4, o = tid & 15;
    float acc = 0.0f;
#pragma unroll
    for (int d2 = 0; d2 < D; d2++)
        acc = fmaf(fmaxf(rows[n][d2], 0.0f), W[d2 * D_OUT + o], acc);
    out[(node0 + n) * D_OUT + o] = acc;
}

// ---------------------------------------------------------------------------
extern "C" void kernel_launch(void* const* d_in, const int* in_sizes, int n_in,
                              void* d_out, int out_size, void* d_ws, size_t ws_size,
                              hipStream_t stream) {
    const float* x    = (const float*)d_in[0];
    const int*   ei   = (const int*)d_in[1];
    const float* ew   = (const float*)d_in[2];
    const float* encW = (const float*)d_in[3];
    const float* encb = (const float*)d_in[4];
    const float* cayB = (const float*)d_in[5];
    const float* decW = (const float*)d_in[6];
    float* out = (float*)d_out;
    const int* src = ei;
    const int* dst = ei + N_EDGES;

    char* w = (char*)d_ws;
    double* GGpart = (double*)w;                       // 32768 B
    float*  avec   = (float*)(w + 32768);              // 256 B reserved
    float*  thetaT = (float*)(w + 33024);              // 16384 B
    int*    counts = (int*)(w + 49408);                // 40000 B
    int*    rowptr = (int*)(w + 89408);                // 40004 B -> pad to 40192
    int*    cursor = (int*)(w + 129600);               // 40000 B -> pad to 40384
    uint2*  edata  = (uint2*)(w + 169984);             // 2560000 B
    float*  b   = (float*)(w + 2729984);
    float*  t0  = b + NM;
    float*  t1  = t0 + NM;
    float*  Xb  = t1 + NM;                             // 5 slots
    float*  Fb  = Xb + 5 * NM;                         // 5 slots

    // setup: theta (block 0) || enc + count (blocks 1..625)
    hipMemsetAsync(counts, 0, N_NODES * sizeof(int), stream);
    setup_kernel<<<626, 1024, 0, stream>>>(cayB, thetaT, x, encW, encb,
                                           b, Xb, t0, dst, counts);
    scan_kernel<<<1, 1024, 0, stream>>>(counts, rowptr, cursor);
    scatter_kernel<<<512, 256, 0, stream>>>(src, dst, ew, cursor, edata);

    const int EW_BLOCKS = (NM / 4 + 255) / 256;   // 625

    // init phase: F[i] = g(X[i]); X[i+1] = F[i]; t ping-pong (g_i reads t_{i%2})
    for (int i = 0; i < 5; i++) {
        float* tin  = (i & 1) ? t1 : t0;
        float* tout = (i < 4) ? ((i & 1) ? t0 : t1) : nullptr;
        g_kernel<<<N_NODES / 4, 256, 0, stream>>>(
            rowptr, edata, tin, b, thetaT, Fb + i * NM,
            (i < 4) ? (Xb + (i + 1) * NM) : nullptr, tout);
    }

    // Anderson phase: combine writes X[k] and t0; g reads t0 (no t_out needed)
    for (int k = 0; k < 5; k++) {
        gg_kernel<<<GG_BLOCKS, 256, 0, stream>>>(Xb, Fb, GGpart);
        solve_kernel<<<1, 256, 0, stream>>>(GGpart, avec);
        combine_kernel<<<EW_BLOCKS, 256, 0, stream>>>(Fb, avec, b, Xb + k * NM, t0);
        if (k < 4)
            g_kernel<<<N_NODES / 4, 256, 0, stream>>>(
                rowptr, edata, t0, b, thetaT, Fb + k * NM, nullptr, nullptr);
    }

    out_kernel<<<N_NODES / 16, 256, 0, stream>>>(Xb + 4 * NM, decW, out);
}

// Round 9
// 464.959 us; speedup vs baseline: 11.7681x; 1.0559x over previous
//
#include <hip/hip_runtime.h>
#include <math.h>

#define N_NODES 10000
#define N_EDGES 320000
#define D 64
#define D_IN 128
#define D_OUT 16
#define NM (N_NODES * D)   // 640000 elements per state vector
#define GG_BLOCKS 256

// ---------------------------------------------------------------------------
// Fused setup: block 0 computes Theta = (I+Om)^-1 (I-Om); blocks 1..625 do
// enc (16 nodes each, one node per wave) + edge counting.
// Theta via 4x4-BLOCKED no-pivot Gauss-Jordan: 16 block-steps x 3 barriers.
// No-pivot validity: every Schur complement of A = I + skew has symmetric
// part >= I; so does its leading 4x4 block => stable 4x4 inverses.
// Theta stored TRANSPOSED: thetaT[k*64 + d] = Theta[d][k].
// ---------------------------------------------------------------------------
__global__ void __launch_bounds__(1024) setup_kernel(
    const float* __restrict__ B, float* __restrict__ thetaT,
    const float* __restrict__ x, const float* __restrict__ encW,
    const float* __restrict__ encb, float* __restrict__ b,
    float* __restrict__ x0, float* __restrict__ t0,
    const int* __restrict__ dst, int* __restrict__ counts) {
    __shared__ float sh[64 * 132 + 16];     // M (stride 132) + Dinv
    const int tid = threadIdx.x;

    if (blockIdx.x == 0) {
        float* Dinv = &sh[64 * 132];
        for (int i = tid; i < 64 * 128; i += 1024) {
            int r = i >> 7, c = i & 127;
            float v;
            if (c < 64) {
                float om = 0.5f * (B[r * 64 + c] - B[c * 64 + r]);
                v = om + (r == c ? 1.0f : 0.0f);
            } else {
                int c2 = c - 64;
                float om = 0.5f * (B[r * 64 + c2] - B[c2 * 64 + r]);
                v = -om + (r == c2 ? 1.0f : 0.0f);
            }
            sh[r * 132 + c] = v;
        }
        const int r  = tid >> 4;            // owned row (64)
        const int cb = (tid & 15) * 8;      // owned 8-col chunk (16)

        for (int kb = 0; kb < 16; ++kb) {
            const int kc = kb * 4;
            __syncthreads();
            // A: thread 0 inverts the 4x4 diagonal block (no pivoting)
            if (tid == 0) {
                float Dm[4][8];
#pragma unroll
                for (int i = 0; i < 4; ++i)
#pragma unroll
                    for (int j = 0; j < 4; ++j) {
                        Dm[i][j]     = sh[(kc + i) * 132 + kc + j];
                        Dm[i][4 + j] = (i == j) ? 1.0f : 0.0f;
                    }
#pragma unroll
                for (int p = 0; p < 4; ++p) {
                    float inv = 1.0f / Dm[p][p];
#pragma unroll
                    for (int c = 0; c < 8; ++c) Dm[p][c] *= inv;
#pragma unroll
                    for (int r2 = 0; r2 < 4; ++r2)
                        if (r2 != p) {
                            float f = Dm[r2][p];
#pragma unroll
                            for (int c = 0; c < 8; ++c)
                                Dm[r2][c] = fmaf(-f, Dm[p][c], Dm[r2][c]);
                        }
                }
#pragma unroll
                for (int i = 0; i < 4; ++i)
#pragma unroll
                    for (int j = 0; j < 4; ++j) Dinv[i * 4 + j] = Dm[i][4 + j];
            }
            __syncthreads();
            // B: pivot rows <- Dinv @ pivot rows, cols kc+4..127 (one col/thread)
            {
                int c = kc + 4 + tid;
                if (c < 128) {
                    float o0 = sh[(kc + 0) * 132 + c];
                    float o1 = sh[(kc + 1) * 132 + c];
                    float o2 = sh[(kc + 2) * 132 + c];
                    float o3 = sh[(kc + 3) * 132 + c];
#pragma unroll
                    for (int i = 0; i < 4; ++i) {
                        float n = Dinv[i * 4 + 0] * o0 + Dinv[i * 4 + 1] * o1 +
                                  Dinv[i * 4 + 2] * o2 + Dinv[i * 4 + 3] * o3;
                        sh[(kc + i) * 132 + c] = n;
                    }
                }
            }
            __syncthreads();
            // C: rank-4 eliminate rows outside block, cols > kc+3
            if (r < kc || r > kc + 3) {
                const float f0 = sh[r * 132 + kc + 0];
                const float f1 = sh[r * 132 + kc + 1];
                const float f2 = sh[r * 132 + kc + 2];
                const float f3 = sh[r * 132 + kc + 3];
                if (cb > kc + 3) {          // chunk fully beyond block: float4 path
#pragma unroll
                    for (int h = 0; h < 2; ++h) {
                        const int c = cb + h * 4;
                        float4 p0 = *(const float4*)&sh[(kc + 0) * 132 + c];
                        float4 p1 = *(const float4*)&sh[(kc + 1) * 132 + c];
                        float4 p2 = *(const float4*)&sh[(kc + 2) * 132 + c];
                        float4 p3 = *(const float4*)&sh[(kc + 3) * 132 + c];
                        float4 v  = *(float4*)&sh[r * 132 + c];
                        v.x = fmaf(-f3, p3.x, fmaf(-f2, p2.x, fmaf(-f1, p1.x, fmaf(-f0, p0.x, v.x))));
                        v.y = fmaf(-f3, p3.y, fmaf(-f2, p2.y, fmaf(-f1, p1.y, fmaf(-f0, p0.y, v.y))));
                        v.z = fmaf(-f3, p3.z, fmaf(-f2, p2.z, fmaf(-f1, p1.z, fmaf(-f0, p0.z, v.z))));
                        v.w = fmaf(-f3, p3.w, fmaf(-f2, p2.w, fmaf(-f1, p1.w, fmaf(-f0, p0.w, v.w))));
                        *(float4*)&sh[r * 132 + c] = v;
                    }
                } else if (cb + 7 > kc + 3) {  // straddling chunk: predicated scalar
#pragma unroll
                    for (int j = 0; j < 8; ++j) {
                        const int c = cb + j;
                        if (c > kc + 3) {
                            float v = sh[r * 132 + c];
                            v = fmaf(-f0, sh[(kc + 0) * 132 + c], v);
                            v = fmaf(-f1, sh[(kc + 1) * 132 + c], v);
                            v = fmaf(-f2, sh[(kc + 2) * 132 + c], v);
                            v = fmaf(-f3, sh[(kc + 3) * 132 + c], v);
                            sh[r * 132 + c] = v;
                        }
                    }
                }                           // chunk fully <= kc+3: dead, skip
            }
        }
        __syncthreads();
        for (int i = tid; i < 64 * 64; i += 1024) {
            int kk = i >> 6, d = i & 63;
            thetaT[i] = sh[d * 132 + 64 + kk];
        }
    } else {
        // ---------------- enc: 16 nodes/block, one node per wave ------------
        const int node0 = (blockIdx.x - 1) * 16;
        sh[tid]        = x[node0 * D_IN + tid];
        sh[tid + 1024] = x[node0 * D_IN + 1024 + tid];
        __syncthreads();
        const int nl = tid >> 6, lane = tid & 63;
        const int node = node0 + nl;
        const float* xr = &sh[nl * D_IN];   // wave-uniform reads -> LDS broadcast
        float acc = encb[lane];
#pragma unroll
        for (int k = 0; k < D_IN; ++k) acc = fmaf(xr[k], encW[k * D + lane], acc);
        b[node * D + lane]  = acc;
        x0[node * D + lane] = acc;
        t0[node * D + lane] = fabsf(acc) + acc;
        // ---------------- count incoming edges ------------------------------
        int e = (blockIdx.x - 1) * 1024 + tid;
        const int stride = 625 * 1024;
        for (; e < N_EDGES; e += stride) atomicAdd(&counts[dst[e]], 1);
    }
}

// ---------------------------------------------------------------------------
// Exclusive scan of counts -> rowptr/cursor.  1024 threads x 10 serial each,
// shfl wave-scan + 16-wave LDS combine: 2 barriers total.
// ---------------------------------------------------------------------------
__global__ void __launch_bounds__(1024) scan_kernel(
    const int* __restrict__ counts, int* __restrict__ rowptr,
    int* __restrict__ cursor) {
    __shared__ int wtot[16];
    const int tid = threadIdx.x;
    const int base = tid * 10;
    int c[10];
    int T = 0;
#pragma unroll
    for (int j = 0; j < 10; ++j) {
        int idx = base + j;
        c[j] = (idx < N_NODES) ? counts[idx] : 0;
        T += c[j];
    }
    int incl = T;                            // wave-inclusive scan
#pragma unroll
    for (int o = 1; o < 64; o <<= 1) {
        int v = __shfl_up(incl, o, 64);
        if ((tid & 63) >= o) incl += v;
    }
    const int wv = tid >> 6;
    if ((tid & 63) == 63) wtot[wv] = incl;
    __syncthreads();
    int wpre = 0;
#pragma unroll
    for (int w2 = 0; w2 < 16; ++w2) wpre += (w2 < wv) ? wtot[w2] : 0;
    int run = wpre + (incl - T);             // global exclusive offset
#pragma unroll
    for (int j = 0; j < 10; ++j) {
        int idx = base + j;
        if (idx < N_NODES) { rowptr[idx] = run; cursor[idx] = run; }
        run += c[j];
    }
    if (tid == 1023) rowptr[N_NODES] = run;  // == N_EDGES
}

__global__ void scatter_kernel(const int* __restrict__ src, const int* __restrict__ dst,
                               const float* __restrict__ ew, int* __restrict__ cursor,
                               uint2* __restrict__ edata) {
    int e = blockIdx.x * blockDim.x + threadIdx.x;
    const int stride = gridDim.x * blockDim.x;
    for (; e < N_EDGES; e += stride) {
        int p = atomicAdd(&cursor[dst[e]], 1);
        edata[p] = make_uint2((unsigned)src[e], __float_as_uint(ew[e]));
    }
}

// ---------------------------------------------------------------------------
// Fused g: F[node] = b + 0.5 * Theta @ (A t_in)[node]   (one wave per node)
// CSR gather (no atomics) into registers; 64x64 matvec via __shfl broadcast
// of the per-lane S values -> NO Srow LDS, only ONE barrier (Th staging),
// waves fully independent afterwards (no block-level degree stragglers).
// ---------------------------------------------------------------------------
__global__ void __launch_bounds__(256) g_kernel(
    const int* __restrict__ rowptr, const uint2* __restrict__ edata,
    const float* __restrict__ t_in, const float* __restrict__ b,
    const float* __restrict__ thetaT, float* __restrict__ F,
    float* __restrict__ Xnext, float* __restrict__ t_out) {
    __shared__ float Th[D * D];
    const int tid = threadIdx.x;
#pragma unroll
    for (int i = 0; i < 4; ++i)              // 4096 floats / 256 thr = 4 float4
        *(float4*)&Th[(i * 256 + tid) * 4] = *(const float4*)&thetaT[(i * 256 + tid) * 4];
    const int ln = tid & 63, wv = tid >> 6;
    const int node = blockIdx.x * 4 + wv;
    __syncthreads();

    float acc = 0.0f;
    int e = rowptr[node];
    const int end = rowptr[node + 1];
    for (; e + 3 < end; e += 4) {           // unroll-4: 4 independent t-row loads in flight
        uint2 a0 = edata[e], a1 = edata[e + 1], a2 = edata[e + 2], a3 = edata[e + 3];
        float v0 = t_in[a0.x * D + ln];
        float v1 = t_in[a1.x * D + ln];
        float v2 = t_in[a2.x * D + ln];
        float v3 = t_in[a3.x * D + ln];
        acc = fmaf(__uint_as_float(a0.y), v0, acc);
        acc = fmaf(__uint_as_float(a1.y), v1, acc);
        acc = fmaf(__uint_as_float(a2.y), v2, acc);
        acc = fmaf(__uint_as_float(a3.y), v3, acc);
    }
    for (; e < end; ++e) {
        uint2 a = edata[e];
        acc = fmaf(__uint_as_float(a.y), t_in[a.x * D + ln], acc);
    }

    float r = 0.0f;
#pragma unroll
    for (int k = 0; k < D; ++k) {           // S[k] broadcast via shuffle
        float sk = __shfl(acc, k, 64);
        r = fmaf(sk, Th[k * D + ln], r);
    }
    const float bb = b[node * D + ln];
    const float v = bb + 0.5f * r;
    F[node * D + ln] = v;
    if (Xnext) Xnext[node * D + ln] = v;
    if (t_out) t_out[node * D + ln] = fabsf(v) + bb;
}

// ---------------------------------------------------------------------------
// Anderson: per-block partials of the GG upper triangle (15 entries) in f64.
// No global atomics: block -> GGpart[blk*16 + p].
// ---------------------------------------------------------------------------
__global__ void gg_kernel(const float* __restrict__ Xb, const float* __restrict__ Fb,
                          double* __restrict__ GGpart) {
    __shared__ double swave[4][16];
    double acc[15];
#pragma unroll
    for (int p = 0; p < 15; p++) acc[p] = 0.0;
    int idx = blockIdx.x * blockDim.x + threadIdx.x;
    const int stride = gridDim.x * blockDim.x;
    for (int i = idx; i < NM; i += stride) {
        float g[5];
#pragma unroll
        for (int j = 0; j < 5; j++) g[j] = Fb[j * NM + i] - Xb[j * NM + i];
        int p = 0;
#pragma unroll
        for (int a = 0; a < 5; a++)
#pragma unroll
            for (int bq = a; bq < 5; bq++) acc[p++] += (double)g[a] * (double)g[bq];
    }
#pragma unroll
    for (int p = 0; p < 15; p++)
        for (int o = 32; o > 0; o >>= 1) acc[p] += __shfl_down(acc[p], o, 64);
    const int wv = threadIdx.x >> 6;
    if ((threadIdx.x & 63) == 0) {
#pragma unroll
        for (int p = 0; p < 15; p++) swave[wv][p] = acc[p];
    }
    __syncthreads();
    if (threadIdx.x < 15) {
        double s = swave[0][threadIdx.x] + swave[1][threadIdx.x] +
                   swave[2][threadIdx.x] + swave[3][threadIdx.x];
        GGpart[blockIdx.x * 16 + threadIdx.x] = s;
    }
}

// ---------------------------------------------------------------------------
// Sum GGpart (16 lanes per entry), then a = (GG + lam I)^-1 1; a /= sum(a).
// ---------------------------------------------------------------------------
__global__ void solve_kernel(const double* __restrict__ GGpart, float* __restrict__ a) {
    __shared__ double GG[16];
    const int tid = threadIdx.x;
    const int p = tid >> 4;
    const int g = tid & 15;
    double s = 0.0;
    if (p < 15) {
        for (int blk = g; blk < GG_BLOCKS; blk += 16) s += GGpart[blk * 16 + p];
    }
#pragma unroll
    for (int o = 8; o > 0; o >>= 1) s += __shfl_down(s, o, 16);
    if (g == 0 && p < 15) GG[p] = s;
    __syncthreads();
    if (tid != 0) return;
    double A[5][5], rhs[5];
    int q = 0;
    for (int r = 0; r < 5; r++)
        for (int c = r; c < 5; c++) { double v = GG[q++]; A[r][c] = v; A[c][r] = v; }
    for (int i = 0; i < 5; i++) { A[i][i] += 1e-4; rhs[i] = 1.0; }
    for (int i = 0; i < 5; i++) {
        int piv = i; double best = fabs(A[i][i]);
        for (int r = i + 1; r < 5; r++) {
            double v = fabs(A[r][i]);
            if (v > best) { best = v; piv = r; }
        }
        if (piv != i) {
            for (int c = 0; c < 5; c++) { double tmp = A[i][c]; A[i][c] = A[piv][c]; A[piv][c] = tmp; }
            double tr = rhs[i]; rhs[i] = rhs[piv]; rhs[piv] = tr;
        }
        double inv = 1.0 / A[i][i];
        for (int c = 0; c < 5; c++) A[i][c] *= inv;
        rhs[i] *= inv;
        for (int r = 0; r < 5; r++)
            if (r != i) {
                double f = A[r][i];
                for (int c = 0; c < 5; c++) A[r][c] -= f * A[i][c];
                rhs[r] -= f * rhs[i];
            }
    }
    double ssum = rhs[0] + rhs[1] + rhs[2] + rhs[3] + rhs[4];
    for (int j = 0; j < 5; j++) a[j] = (float)(rhs[j] / ssum);
}

// ---------------------------------------------------------------------------
// Xk = sum_j a[j] * F[j];  fused t = |Xk| + b for the following g.
// ---------------------------------------------------------------------------
__global__ void combine_kernel(const float* __restrict__ Fb, const float* __restrict__ a,
                               const float* __restrict__ b, float* __restrict__ Xk,
                               float* __restrict__ t) {
    __shared__ float as[5];
    if (threadIdx.x < 5) as[threadIdx.x] = a[threadIdx.x];
    __syncthreads();
    int i = blockIdx.x * blockDim.x + threadIdx.x;
    if (i >= NM / 4) return;
    float4 r = {0.f, 0.f, 0.f, 0.f};
#pragma unroll
    for (int j = 0; j < 5; j++) {
        const float4 f = ((const float4*)(Fb + j * NM))[i];
        float aj = as[j];
        r.x = fmaf(aj, f.x, r.x);
        r.y = fmaf(aj, f.y, r.y);
        r.z = fmaf(aj, f.z, r.z);
        r.w = fmaf(aj, f.w, r.w);
    }
    ((float4*)Xk)[i] = r;
    const float4 bv = ((const float4*)b)[i];
    float4 tv;
    tv.x = fabsf(r.x) + bv.x;
    tv.y = fabsf(r.y) + bv.y;
    tv.z = fabsf(r.z) + bv.z;
    tv.w = fabsf(r.w) + bv.w;
    ((float4*)t)[i] = tv;
}

// ---------------------------------------------------------------------------
// out[node][o] = sum_d relu(u[node][d]) * decW[d][o]
// ---------------------------------------------------------------------------
__global__ void out_kernel(const float* __restrict__ u, const float* __restrict__ decW,
                           float* __restrict__ out) {
    __shared__ float W[D * D_OUT];
    __shared__ float rows[16][D + 1];
    const int tid = threadIdx.x;
    for (int i = tid; i < D * D_OUT; i += 256) W[i] = decW[i];
    const int node0 = blockIdx.x * 16;
    for (int i = tid; i < 16 * D; i += 256) {
        int n = i >> 6, d = i & 63;
        rows[n][d] = u[(node0 + n) * D + d];
    }
    __syncthreads();
    const int n = tid >> 4, o = tid & 15;
    float acc = 0.0f;
#pragma unroll
    for (int d2 = 0; d2 < D; d2++)
        acc = fmaf(fmaxf(rows[n][d2], 0.0f), W[d2 * D_OUT + o], acc);
    out[(node0 + n) * D_OUT + o] = acc;
}

// ---------------------------------------------------------------------------
extern "C" void kernel_launch(void* const* d_in, const int* in_sizes, int n_in,
                              void* d_out, int out_size, void* d_ws, size_t ws_size,
                              hipStream_t stream) {
    const float* x    = (const float*)d_in[0];
    const int*   ei   = (const int*)d_in[1];
    const float* ew   = (const float*)d_in[2];
    const float* encW = (const float*)d_in[3];
    const float* encb = (const float*)d_in[4];
    const float* cayB = (const float*)d_in[5];
    const float* decW = (const float*)d_in[6];
    float* out = (float*)d_out;
    const int* src = ei;
    const int* dst = ei + N_EDGES;

    char* w = (char*)d_ws;
    double* GGpart = (double*)w;                       // 32768 B
    float*  avec   = (float*)(w + 32768);              // 256 B reserved
    float*  thetaT = (float*)(w + 33024);              // 16384 B
    int*    counts = (int*)(w + 49408);                // 40000 B
    int*    rowptr = (int*)(w + 89408);                // 40004 B -> pad to 40192
    int*    cursor = (int*)(w + 129600);               // 40000 B -> pad to 40384
    uint2*  edata  = (uint2*)(w + 169984);             // 2560000 B
    float*  b   = (float*)(w + 2729984);
    float*  t0  = b + NM;
    float*  t1  = t0 + NM;
    float*  Xb  = t1 + NM;                             // 5 slots
    float*  Fb  = Xb + 5 * NM;                         // 5 slots

    // setup: theta (block 0) || enc + count (blocks 1..625)
    hipMemsetAsync(counts, 0, N_NODES * sizeof(int), stream);
    setup_kernel<<<626, 1024, 0, stream>>>(cayB, thetaT, x, encW, encb,
                                           b, Xb, t0, dst, counts);
    scan_kernel<<<1, 1024, 0, stream>>>(counts, rowptr, cursor);
    scatter_kernel<<<512, 256, 0, stream>>>(src, dst, ew, cursor, edata);

    const int EW_BLOCKS = (NM / 4 + 255) / 256;   // 625

    // init phase: F[i] = g(X[i]); X[i+1] = F[i]; t ping-pong (g_i reads t_{i%2})
    for (int i = 0; i < 5; i++) {
        float* tin  = (i & 1) ? t1 : t0;
        float* tout = (i < 4) ? ((i & 1) ? t0 : t1) : nullptr;
        g_kernel<<<N_NODES / 4, 256, 0, stream>>>(
            rowptr, edata, tin, b, thetaT, Fb + i * NM,
            (i < 4) ? (Xb + (i + 1) * NM) : nullptr, tout);
    }

    // Anderson phase: combine writes X[k] and t0; g reads t0 (no t_out needed)
    for (int k = 0; k < 5; k++) {
        gg_kernel<<<GG_BLOCKS, 256, 0, stream>>>(Xb, Fb, GGpart);
        solve_kernel<<<1, 256, 0, stream>>>(GGpart, avec);
        combine_kernel<<<EW_BLOCKS, 256, 0, stream>>>(Fb, avec, b, Xb + k * NM, t0);
        if (k < 4)
            g_kernel<<<N_NODES / 4, 256, 0, stream>>>(
                rowptr, edata, t0, b, thetaT, Fb + k * NM, nullptr, nullptr);
    }

    out_kernel<<<N_NODES / 16, 256, 0, stream>>>(Xb + 4 * NM, decW, out);
}

// Round 14
// 422.893 us; speedup vs baseline: 12.9387x; 1.0995x over previous
//
#include <hip/hip_runtime.h>
#include <math.h>

#define N_NODES 10000
#define N_EDGES 320000
#define D 64
#define D_IN 128
#define D_OUT 16
#define NM (N_NODES * D)   // 640000 elements per state vector
#define GG_BLOCKS 256

// ---------------------------------------------------------------------------
// Fused setup: block 0 computes Theta = (I+Om)^-1 (I-Om); blocks 1..625 do
// enc (16 nodes each, one node per wave) + edge counting.
// Theta via 4x4-BLOCKED no-pivot Gauss-Jordan, 16 steps x 3 barriers.
// Phase A (4x4 diag-block inverse) is WAVE-PARALLEL: 16 lanes hold one
// element each and run in-place GJ with __shfl broadcasts (no LDS latency
// chain).  No-pivot validity: every Schur complement of A = I + skew has
// symmetric part >= I, as does each leading 4x4 block.
// Theta stored TRANSPOSED: thetaT[k*64 + d] = Theta[d][k].
// ---------------------------------------------------------------------------
__global__ void __launch_bounds__(1024) setup_kernel(
    const float* __restrict__ B, float* __restrict__ thetaT,
    const float* __restrict__ x, const float* __restrict__ encW,
    const float* __restrict__ encb, float* __restrict__ b,
    float* __restrict__ x0, float* __restrict__ t0,
    const int* __restrict__ dst, int* __restrict__ counts) {
    __shared__ float sh[64 * 132 + 16];     // M (stride 132) + Dinv
    const int tid = threadIdx.x;

    if (blockIdx.x == 0) {
        float* Dinv = &sh[64 * 132];
        for (int i = tid; i < 64 * 128; i += 1024) {
            int r = i >> 7, c = i & 127;
            float v;
            if (c < 64) {
                float om = 0.5f * (B[r * 64 + c] - B[c * 64 + r]);
                v = om + (r == c ? 1.0f : 0.0f);
            } else {
                int c2 = c - 64;
                float om = 0.5f * (B[r * 64 + c2] - B[c2 * 64 + r]);
                v = -om + (r == c2 ? 1.0f : 0.0f);
            }
            sh[r * 132 + c] = v;
        }
        const int r  = tid >> 4;            // owned row (64)
        const int cb = (tid & 15) * 8;      // owned 8-col chunk (16)

        for (int kb = 0; kb < 16; ++kb) {
            const int kc = kb * 4;
            __syncthreads();
            // A: lanes 0..15 invert the 4x4 diag block, in-place GJ via shfl.
            // new(p,p)=d; new(p,j)=a*d; new(i,p)=-a*d; new(i,j)=a-aip*apj*d.
            if (tid < 16) {
                const int i = tid >> 2, j = tid & 3;
                float a = sh[(kc + i) * 132 + kc + j];
#pragma unroll
                for (int p = 0; p < 4; ++p) {
                    float app = __shfl(a, p * 5, 16);
                    float apj = __shfl(a, p * 4 + j, 16);
                    float aip = __shfl(a, i * 4 + p, 16);
                    float d = 1.0f / app;
                    float na;
                    if (i == p)      na = (j == p) ? d : a * d;
                    else if (j == p) na = -a * d;
                    else             na = fmaf(-aip * d, apj, a);
                    a = na;
                }
                Dinv[tid] = a;
            }
            __syncthreads();
            // B: pivot rows <- Dinv @ pivot rows, cols kc+4..127 (one col/thread)
            {
                int c = kc + 4 + tid;
                if (c < 128) {
                    float o0 = sh[(kc + 0) * 132 + c];
                    float o1 = sh[(kc + 1) * 132 + c];
                    float o2 = sh[(kc + 2) * 132 + c];
                    float o3 = sh[(kc + 3) * 132 + c];
#pragma unroll
                    for (int i = 0; i < 4; ++i) {
                        float n = Dinv[i * 4 + 0] * o0 + Dinv[i * 4 + 1] * o1 +
                                  Dinv[i * 4 + 2] * o2 + Dinv[i * 4 + 3] * o3;
                        sh[(kc + i) * 132 + c] = n;
                    }
                }
            }
            __syncthreads();
            // C: rank-4 eliminate rows outside block, cols > kc+3
            if (r < kc || r > kc + 3) {
                const float f0 = sh[r * 132 + kc + 0];
                const float f1 = sh[r * 132 + kc + 1];
                const float f2 = sh[r * 132 + kc + 2];
                const float f3 = sh[r * 132 + kc + 3];
                if (cb > kc + 3) {          // chunk fully beyond block: float4 path
#pragma unroll
                    for (int h = 0; h < 2; ++h) {
                        const int c = cb + h * 4;
                        float4 p0 = *(const float4*)&sh[(kc + 0) * 132 + c];
                        float4 p1 = *(const float4*)&sh[(kc + 1) * 132 + c];
                        float4 p2 = *(const float4*)&sh[(kc + 2) * 132 + c];
                        float4 p3 = *(const float4*)&sh[(kc + 3) * 132 + c];
                        float4 v  = *(float4*)&sh[r * 132 + c];
                        v.x = fmaf(-f3, p3.x, fmaf(-f2, p2.x, fmaf(-f1, p1.x, fmaf(-f0, p0.x, v.x))));
                        v.y = fmaf(-f3, p3.y, fmaf(-f2, p2.y, fmaf(-f1, p1.y, fmaf(-f0, p0.y, v.y))));
                        v.z = fmaf(-f3, p3.z, fmaf(-f2, p2.z, fmaf(-f1, p1.z, fmaf(-f0, p0.z, v.z))));
                        v.w = fmaf(-f3, p3.w, fmaf(-f2, p2.w, fmaf(-f1, p1.w, fmaf(-f0, p0.w, v.w))));
                        *(float4*)&sh[r * 132 + c] = v;
                    }
                } else if (cb + 7 > kc + 3) {  // straddling chunk: predicated scalar
#pragma unroll
                    for (int j = 0; j < 8; ++j) {
                        const int c = cb + j;
                        if (c > kc + 3) {
                            float v = sh[r * 132 + c];
                            v = fmaf(-f0, sh[(kc + 0) * 132 + c], v);
                            v = fmaf(-f1, sh[(kc + 1) * 132 + c], v);
                            v = fmaf(-f2, sh[(kc + 2) * 132 + c], v);
                            v = fmaf(-f3, sh[(kc + 3) * 132 + c], v);
                            sh[r * 132 + c] = v;
                        }
                    }
                }                           // chunk fully <= kc+3: dead, skip
            }
        }
        __syncthreads();
        for (int i = tid; i < 64 * 64; i += 1024) {
            int kk = i >> 6, d = i & 63;
            thetaT[i] = sh[d * 132 + 64 + kk];
        }
    } else {
        // ---------------- enc: 16 nodes/block, one node per wave ------------
        const int node0 = (blockIdx.x - 1) * 16;
        sh[tid]        = x[node0 * D_IN + tid];
        sh[tid + 1024] = x[node0 * D_IN + 1024 + tid];
        __syncthreads();
        const int nl = tid >> 6, lane = tid & 63;
        const int node = node0 + nl;
        const float* xr = &sh[nl * D_IN];   // wave-uniform reads -> LDS broadcast
        float acc = encb[lane];
#pragma unroll
        for (int k = 0; k < D_IN; ++k) acc = fmaf(xr[k], encW[k * D + lane], acc);
        b[node * D + lane]  = acc;
        x0[node * D + lane] = acc;
        t0[node * D + lane] = fabsf(acc) + acc;
        // ---------------- count incoming edges ------------------------------
        int e = (blockIdx.x - 1) * 1024 + tid;
        const int stride = 625 * 1024;
        for (; e < N_EDGES; e += stride) atomicAdd(&counts[dst[e]], 1);
    }
}

// ---------------------------------------------------------------------------
// Exclusive scan of counts -> rowptr/cursor.  1024 threads x 10 serial each,
// shfl wave-scan + 16-wave LDS combine: 2 barriers total.
// ---------------------------------------------------------------------------
__global__ void __launch_bounds__(1024) scan_kernel(
    const int* __restrict__ counts, int* __restrict__ rowptr,
    int* __restrict__ cursor) {
    __shared__ int wtot[16];
    const int tid = threadIdx.x;
    const int base = tid * 10;
    int c[10];
    int T = 0;
#pragma unroll
    for (int j = 0; j < 10; ++j) {
        int idx = base + j;
        c[j] = (idx < N_NODES) ? counts[idx] : 0;
        T += c[j];
    }
    int incl = T;                            // wave-inclusive scan
#pragma unroll
    for (int o = 1; o < 64; o <<= 1) {
        int v = __shfl_up(incl, o, 64);
        if ((tid & 63) >= o) incl += v;
    }
    const int wv = tid >> 6;
    if ((tid & 63) == 63) wtot[wv] = incl;
    __syncthreads();
    int wpre = 0;
#pragma unroll
    for (int w2 = 0; w2 < 16; ++w2) wpre += (w2 < wv) ? wtot[w2] : 0;
    int run = wpre + (incl - T);             // global exclusive offset
#pragma unroll
    for (int j = 0; j < 10; ++j) {
        int idx = base + j;
        if (idx < N_NODES) { rowptr[idx] = run; cursor[idx] = run; }
        run += c[j];
    }
    if (tid == 1023) rowptr[N_NODES] = run;  // == N_EDGES
}

__global__ void scatter_kernel(const int* __restrict__ src, const int* __restrict__ dst,
                               const float* __restrict__ ew, int* __restrict__ cursor,
                               uint2* __restrict__ edata) {
    int e = blockIdx.x * blockDim.x + threadIdx.x;
    const int stride = gridDim.x * blockDim.x;
    for (; e < N_EDGES; e += stride) {
        int p = atomicAdd(&cursor[dst[e]], 1);
        edata[p] = make_uint2((unsigned)src[e], __float_as_uint(ew[e]));
    }
}

// ---------------------------------------------------------------------------
// Fused g: F[node] = b + 0.5 * Theta @ (A t_in)[node]   (one wave per node)
// 512-thr blocks (8 nodes) to amortize Th staging; CSR gather unroll-8 for
// deep MLP; 64x64 matvec via __shfl broadcast (no Srow LDS, one barrier).
// Optional dual-writes: Xnext = F (init history), t_out = |F| + b (next t).
// ---------------------------------------------------------------------------
__global__ void __launch_bounds__(512) g_kernel(
    const int* __restrict__ rowptr, const uint2* __restrict__ edata,
    const float* __restrict__ t_in, const float* __restrict__ b,
    const float* __restrict__ thetaT, float* __restrict__ F,
    float* __restrict__ Xnext, float* __restrict__ t_out) {
    __shared__ float Th[D * D];
    const int tid = threadIdx.x;
#pragma unroll
    for (int i = 0; i < 2; ++i)              // 4096 floats / 512 thr = 2 float4
        *(float4*)&Th[(i * 512 + tid) * 4] = *(const float4*)&thetaT[(i * 512 + tid) * 4];
    const int ln = tid & 63, wv = tid >> 6;  // 8 waves
    const int node = blockIdx.x * 8 + wv;
    __syncthreads();

    float acc = 0.0f;
    int e = rowptr[node];
    const int end = rowptr[node + 1];
    for (; e + 7 < end; e += 8) {            // unroll-8: 8 gathers in flight
        uint2 a0 = edata[e + 0], a1 = edata[e + 1], a2 = edata[e + 2], a3 = edata[e + 3];
        uint2 a4 = edata[e + 4], a5 = edata[e + 5], a6 = edata[e + 6], a7 = edata[e + 7];
        float v0 = t_in[a0.x * D + ln];
        float v1 = t_in[a1.x * D + ln];
        float v2 = t_in[a2.x * D + ln];
        float v3 = t_in[a3.x * D + ln];
        float v4 = t_in[a4.x * D + ln];
        float v5 = t_in[a5.x * D + ln];
        float v6 = t_in[a6.x * D + ln];
        float v7 = t_in[a7.x * D + ln];
        acc = fmaf(__uint_as_float(a0.y), v0, acc);
        acc = fmaf(__uint_as_float(a1.y), v1, acc);
        acc = fmaf(__uint_as_float(a2.y), v2, acc);
        acc = fmaf(__uint_as_float(a3.y), v3, acc);
        acc = fmaf(__uint_as_float(a4.y), v4, acc);
        acc = fmaf(__uint_as_float(a5.y), v5, acc);
        acc = fmaf(__uint_as_float(a6.y), v6, acc);
        acc = fmaf(__uint_as_float(a7.y), v7, acc);
    }
    for (; e + 3 < end; e += 4) {
        uint2 a0 = edata[e + 0], a1 = edata[e + 1], a2 = edata[e + 2], a3 = edata[e + 3];
        float v0 = t_in[a0.x * D + ln];
        float v1 = t_in[a1.x * D + ln];
        float v2 = t_in[a2.x * D + ln];
        float v3 = t_in[a3.x * D + ln];
        acc = fmaf(__uint_as_float(a0.y), v0, acc);
        acc = fmaf(__uint_as_float(a1.y), v1, acc);
        acc = fmaf(__uint_as_float(a2.y), v2, acc);
        acc = fmaf(__uint_as_float(a3.y), v3, acc);
    }
    for (; e < end; ++e) {
        uint2 a = edata[e];
        acc = fmaf(__uint_as_float(a.y), t_in[a.x * D + ln], acc);
    }

    float r = 0.0f;
#pragma unroll
    for (int k = 0; k < D; ++k) {           // S[k] broadcast via shuffle
        float sk = __shfl(acc, k, 64);
        r = fmaf(sk, Th[k * D + ln], r);
    }
    const float bb = b[node * D + ln];
    const float v = bb + 0.5f * r;
    F[node * D + ln] = v;
    if (Xnext) Xnext[node * D + ln] = v;
    if (t_out) t_out[node * D + ln] = fabsf(v) + bb;
}

// ---------------------------------------------------------------------------
// Anderson: per-block partials of the GG upper triangle (15 entries) in f64.
// float4 streams (10 per iteration) for load efficiency; no global atomics.
// ---------------------------------------------------------------------------
__global__ void gg_kernel(const float* __restrict__ Xb, const float* __restrict__ Fb,
                          double* __restrict__ GGpart) {
    __shared__ double swave[4][16];
    double acc[15];
#pragma unroll
    for (int p = 0; p < 15; p++) acc[p] = 0.0;
    int idx = blockIdx.x * blockDim.x + threadIdx.x;
    const int stride = gridDim.x * blockDim.x;
    for (int i = idx; i < NM / 4; i += stride) {
        float4 g[5];
#pragma unroll
        for (int j = 0; j < 5; j++) {
            const float4 f = ((const float4*)(Fb + j * NM))[i];
            const float4 xv = ((const float4*)(Xb + j * NM))[i];
            g[j] = make_float4(f.x - xv.x, f.y - xv.y, f.z - xv.z, f.w - xv.w);
        }
        int p = 0;
#pragma unroll
        for (int a = 0; a < 5; a++)
#pragma unroll
            for (int bq = a; bq < 5; bq++) {
                acc[p] += (double)g[a].x * (double)g[bq].x
                        + (double)g[a].y * (double)g[bq].y
                        + (double)g[a].z * (double)g[bq].z
                        + (double)g[a].w * (double)g[bq].w;
                p++;
            }
    }
#pragma unroll
    for (int p = 0; p < 15; p++)
        for (int o = 32; o > 0; o >>= 1) acc[p] += __shfl_down(acc[p], o, 64);
    const int wv = threadIdx.x >> 6;
    if ((threadIdx.x & 63) == 0) {
#pragma unroll
        for (int p = 0; p < 15; p++) swave[wv][p] = acc[p];
    }
    __syncthreads();
    if (threadIdx.x < 15) {
        double s = swave[0][threadIdx.x] + swave[1][threadIdx.x] +
                   swave[2][threadIdx.x] + swave[3][threadIdx.x];
        GGpart[blockIdx.x * 16 + threadIdx.x] = s;
    }
}

// ---------------------------------------------------------------------------
// Sum GGpart (16 lanes per entry), then a = (GG + lam I)^-1 1; a /= sum(a).
// ---------------------------------------------------------------------------
__global__ void solve_kernel(const double* __restrict__ GGpart, float* __restrict__ a) {
    __shared__ double GG[16];
    const int tid = threadIdx.x;
    const int p = tid >> 4;
    const int g = tid & 15;
    double s = 0.0;
    if (p < 15) {
        for (int blk = g; blk < GG_BLOCKS; blk += 16) s += GGpart[blk * 16 + p];
    }
#pragma unroll
    for (int o = 8; o > 0; o >>= 1) s += __shfl_down(s, o, 16);
    if (g == 0 && p < 15) GG[p] = s;
    __syncthreads();
    if (tid != 0) return;
    double A[5][5], rhs[5];
    int q = 0;
    for (int r = 0; r < 5; r++)
        for (int c = r; c < 5; c++) { double v = GG[q++]; A[r][c] = v; A[c][r] = v; }
    for (int i = 0; i < 5; i++) { A[i][i] += 1e-4; rhs[i] = 1.0; }
    for (int i = 0; i < 5; i++) {
        int piv = i; double best = fabs(A[i][i]);
        for (int r = i + 1; r < 5; r++) {
            double v = fabs(A[r][i]);
            if (v > best) { best = v; piv = r; }
        }
        if (piv != i) {
            for (int c = 0; c < 5; c++) { double tmp = A[i][c]; A[i][c] = A[piv][c]; A[piv][c] = tmp; }
            double tr = rhs[i]; rhs[i] = rhs[piv]; rhs[piv] = tr;
        }
        double inv = 1.0 / A[i][i];
        for (int c = 0; c < 5; c++) A[i][c] *= inv;
        rhs[i] *= inv;
        for (int r = 0; r < 5; r++)
            if (r != i) {
                double f = A[r][i];
                for (int c = 0; c < 5; c++) A[r][c] -= f * A[i][c];
                rhs[r] -= f * rhs[i];
            }
    }
    double ssum = rhs[0] + rhs[1] + rhs[2] + rhs[3] + rhs[4];
    for (int j = 0; j < 5; j++) a[j] = (float)(rhs[j] / ssum);
}

// ---------------------------------------------------------------------------
// Xk = sum_j a[j] * F[j];  fused t = |Xk| + b for the following g.
// ---------------------------------------------------------------------------
__global__ void combine_kernel(const float* __restrict__ Fb, const float* __restrict__ a,
                               const float* __restrict__ b, float* __restrict__ Xk,
                               float* __restrict__ t) {
    __shared__ float as[5];
    if (threadIdx.x < 5) as[threadIdx.x] = a[threadIdx.x];
    __syncthreads();
    int i = blockIdx.x * blockDim.x + threadIdx.x;
    if (i >= NM / 4) return;
    float4 r = {0.f, 0.f, 0.f, 0.f};
#pragma unroll
    for (int j = 0; j < 5; j++) {
        const float4 f = ((const float4*)(Fb + j * NM))[i];
        float aj = as[j];
        r.x = fmaf(aj, f.x, r.x);
        r.y = fmaf(aj, f.y, r.y);
        r.z = fmaf(aj, f.z, r.z);
        r.w = fmaf(aj, f.w, r.w);
    }
    ((float4*)Xk)[i] = r;
    const float4 bv = ((const float4*)b)[i];
    float4 tv;
    tv.x = fabsf(r.x) + bv.x;
    tv.y = fabsf(r.y) + bv.y;
    tv.z = fabsf(r.z) + bv.z;
    tv.w = fabsf(r.w) + bv.w;
    ((float4*)t)[i] = tv;
}

// ---------------------------------------------------------------------------
// out[node][o] = sum_d relu(u[node][d]) * decW[d][o]
// ---------------------------------------------------------------------------
__global__ void out_kernel(const float* __restrict__ u, const float* __restrict__ decW,
                           float* __restrict__ out) {
    __shared__ float W[D * D_OUT];
    __shared__ float rows[16][D + 1];
    const int tid = threadIdx.x;
    for (int i = tid; i < D * D_OUT; i += 256) W[i] = decW[i];
    const int node0 = blockIdx.x * 16;
    for (int i = tid; i < 16 * D; i += 256) {
        int n = i >> 6, d = i & 63;
        rows[n][d] = u[(node0 + n) * D + d];
    }
    __syncthreads();
    const int n = tid >> 4, o = tid & 15;
    float acc = 0.0f;
#pragma unroll
    for (int d2 = 0; d2 < D; d2++)
        acc = fmaf(fmaxf(rows[n][d2], 0.0f), W[d2 * D_OUT + o], acc);
    out[(node0 + n) * D_OUT + o] = acc;
}

// ---------------------------------------------------------------------------
extern "C" void kernel_launch(void* const* d_in, const int* in_sizes, int n_in,
                              void* d_out, int out_size, void* d_ws, size_t ws_size,
                              hipStream_t stream) {
    const float* x    = (const float*)d_in[0];
    const int*   ei   = (const int*)d_in[1];
    const float* ew   = (const float*)d_in[2];
    const float* encW = (const float*)d_in[3];
    const float* encb = (const float*)d_in[4];
    const float* cayB = (const float*)d_in[5];
    const float* decW = (const float*)d_in[6];
    float* out = (float*)d_out;
    const int* src = ei;
    const int* dst = ei + N_EDGES;

    char* w = (char*)d_ws;
    double* GGpart = (double*)w;                       // 32768 B
    float*  avec   = (float*)(w + 32768);              // 256 B reserved
    float*  thetaT = (float*)(w + 33024);              // 16384 B
    int*    counts = (int*)(w + 49408);                // 40000 B
    int*    rowptr = (int*)(w + 89408);                // 40004 B -> pad to 40192
    int*    cursor = (int*)(w + 129600);               // 40000 B -> pad to 40384
    uint2*  edata  = (uint2*)(w + 169984);             // 2560000 B
    float*  b   = (float*)(w + 2729984);
    float*  t0  = b + NM;
    float*  t1  = t0 + NM;
    float*  Xb  = t1 + NM;                             // 5 slots
    float*  Fb  = Xb + 5 * NM;                         // 5 slots

    // setup: theta (block 0) || enc + count (blocks 1..625)
    hipMemsetAsync(counts, 0, N_NODES * sizeof(int), stream);
    setup_kernel<<<626, 1024, 0, stream>>>(cayB, thetaT, x, encW, encb,
                                           b, Xb, t0, dst, counts);
    scan_kernel<<<1, 1024, 0, stream>>>(counts, rowptr, cursor);
    scatter_kernel<<<512, 256, 0, stream>>>(src, dst, ew, cursor, edata);

    const int EW_BLOCKS = (NM / 4 + 255) / 256;   // 625

    // init phase: F[i] = g(X[i]); X[i+1] = F[i]; t ping-pong (g_i reads t_{i%2})
    for (int i = 0; i < 5; i++) {
        float* tin  = (i & 1) ? t1 : t0;
        float* tout = (i < 4) ? ((i & 1) ? t0 : t1) : nullptr;
        g_kernel<<<N_NODES / 8, 512, 0, stream>>>(
            rowptr, edata, tin, b, thetaT, Fb + i * NM,
            (i < 4) ? (Xb + (i + 1) * NM) : nullptr, tout);
    }

    // Anderson phase: combine writes X[k] and t0; g reads t0 (no t_out needed)
    for (int k = 0; k < 5; k++) {
        gg_kernel<<<GG_BLOCKS, 256, 0, stream>>>(Xb, Fb, GGpart);
        solve_kernel<<<1, 256, 0, stream>>>(GGpart, avec);
        combine_kernel<<<EW_BLOCKS, 256, 0, stream>>>(Fb, avec, b, Xb + k * NM, t0);
        if (k < 4)
            g_kernel<<<N_NODES / 8, 512, 0, stream>>>(
                rowptr, edata, t0, b, thetaT, Fb + k * NM, nullptr, nullptr);
    }

    out_kernel<<<N_NODES / 16, 256, 0, stream>>>(Xb + 4 * NM, decW, out);
}

// Round 15
// 421.131 us; speedup vs baseline: 12.9929x; 1.0042x over previous
//
#include <hip/hip_runtime.h>
#include <math.h>

#define N_NODES 10000
#define N_EDGES 320000
#define D 64
#define D_IN 128
#define D_OUT 16
#define NM (N_NODES * D)   // 640000 elements per state vector
#define GG_BLOCKS 256

// ---------------------------------------------------------------------------
// Fused setup: block 0 computes Theta = (I+Om)^-1 (I-Om); blocks 1..625 do
// enc (16 nodes each, one node per wave) + edge counting.
// Theta via 4x4-BLOCKED no-pivot Gauss-Jordan, 16 steps x 3 barriers.
// Phase A (4x4 diag-block inverse) is WAVE-PARALLEL: 16 lanes hold one
// element each and run in-place GJ with __shfl broadcasts.
// No-pivot validity: every Schur complement of A = I + skew has symmetric
// part >= I, as does each leading 4x4 block.
// Theta stored TRANSPOSED: thetaT[k*64 + d] = Theta[d][k].
// ---------------------------------------------------------------------------
__global__ void __launch_bounds__(1024) setup_kernel(
    const float* __restrict__ B, float* __restrict__ thetaT,
    const float* __restrict__ x, const float* __restrict__ encW,
    const float* __restrict__ encb, float* __restrict__ b,
    float* __restrict__ x0, float* __restrict__ t0,
    const int* __restrict__ dst, int* __restrict__ counts) {
    __shared__ float sh[64 * 132 + 16];     // M (stride 132) + Dinv
    const int tid = threadIdx.x;

    if (blockIdx.x == 0) {
        float* Dinv = &sh[64 * 132];
        for (int i = tid; i < 64 * 128; i += 1024) {
            int r = i >> 7, c = i & 127;
            float v;
            if (c < 64) {
                float om = 0.5f * (B[r * 64 + c] - B[c * 64 + r]);
                v = om + (r == c ? 1.0f : 0.0f);
            } else {
                int c2 = c - 64;
                float om = 0.5f * (B[r * 64 + c2] - B[c2 * 64 + r]);
                v = -om + (r == c2 ? 1.0f : 0.0f);
            }
            sh[r * 132 + c] = v;
        }
        const int r  = tid >> 4;            // owned row (64)
        const int cb = (tid & 15) * 8;      // owned 8-col chunk (16)

        for (int kb = 0; kb < 16; ++kb) {
            const int kc = kb * 4;
            __syncthreads();
            // A: lanes 0..15 invert the 4x4 diag block, in-place GJ via shfl.
            if (tid < 16) {
                const int i = tid >> 2, j = tid & 3;
                float a = sh[(kc + i) * 132 + kc + j];
#pragma unroll
                for (int p = 0; p < 4; ++p) {
                    float app = __shfl(a, p * 5, 16);
                    float apj = __shfl(a, p * 4 + j, 16);
                    float aip = __shfl(a, i * 4 + p, 16);
                    float d = 1.0f / app;
                    float na;
                    if (i == p)      na = (j == p) ? d : a * d;
                    else if (j == p) na = -a * d;
                    else             na = fmaf(-aip * d, apj, a);
                    a = na;
                }
                Dinv[tid] = a;
            }
            __syncthreads();
            // B: pivot rows <- Dinv @ pivot rows, cols kc+4..127 (one col/thread)
            {
                int c = kc + 4 + tid;
                if (c < 128) {
                    float o0 = sh[(kc + 0) * 132 + c];
                    float o1 = sh[(kc + 1) * 132 + c];
                    float o2 = sh[(kc + 2) * 132 + c];
                    float o3 = sh[(kc + 3) * 132 + c];
#pragma unroll
                    for (int i = 0; i < 4; ++i) {
                        float n = Dinv[i * 4 + 0] * o0 + Dinv[i * 4 + 1] * o1 +
                                  Dinv[i * 4 + 2] * o2 + Dinv[i * 4 + 3] * o3;
                        sh[(kc + i) * 132 + c] = n;
                    }
                }
            }
            __syncthreads();
            // C: rank-4 eliminate rows outside block, cols > kc+3
            if (r < kc || r > kc + 3) {
                const float f0 = sh[r * 132 + kc + 0];
                const float f1 = sh[r * 132 + kc + 1];
                const float f2 = sh[r * 132 + kc + 2];
                const float f3 = sh[r * 132 + kc + 3];
                if (cb > kc + 3) {          // chunk fully beyond block: float4 path
#pragma unroll
                    for (int h = 0; h < 2; ++h) {
                        const int c = cb + h * 4;
                        float4 p0 = *(const float4*)&sh[(kc + 0) * 132 + c];
                        float4 p1 = *(const float4*)&sh[(kc + 1) * 132 + c];
                        float4 p2 = *(const float4*)&sh[(kc + 2) * 132 + c];
                        float4 p3 = *(const float4*)&sh[(kc + 3) * 132 + c];
                        float4 v  = *(float4*)&sh[r * 132 + c];
                        v.x = fmaf(-f3, p3.x, fmaf(-f2, p2.x, fmaf(-f1, p1.x, fmaf(-f0, p0.x, v.x))));
                        v.y = fmaf(-f3, p3.y, fmaf(-f2, p2.y, fmaf(-f1, p1.y, fmaf(-f0, p0.y, v.y))));
                        v.z = fmaf(-f3, p3.z, fmaf(-f2, p2.z, fmaf(-f1, p1.z, fmaf(-f0, p0.z, v.z))));
                        v.w = fmaf(-f3, p3.w, fmaf(-f2, p2.w, fmaf(-f1, p1.w, fmaf(-f0, p0.w, v.w))));
                        *(float4*)&sh[r * 132 + c] = v;
                    }
                } else if (cb + 7 > kc + 3) {  // straddling chunk: predicated scalar
#pragma unroll
                    for (int j = 0; j < 8; ++j) {
                        const int c = cb + j;
                        if (c > kc + 3) {
                            float v = sh[r * 132 + c];
                            v = fmaf(-f0, sh[(kc + 0) * 132 + c], v);
                            v = fmaf(-f1, sh[(kc + 1) * 132 + c], v);
                            v = fmaf(-f2, sh[(kc + 2) * 132 + c], v);
                            v = fmaf(-f3, sh[(kc + 3) * 132 + c], v);
                            sh[r * 132 + c] = v;
                        }
                    }
                }                           // chunk fully <= kc+3: dead, skip
            }
        }
        __syncthreads();
        for (int i = tid; i < 64 * 64; i += 1024) {
            int kk = i >> 6, d = i & 63;
            thetaT[i] = sh[d * 132 + 64 + kk];
        }
    } else {
        // ---------------- enc: 16 nodes/block, one node per wave ------------
        const int node0 = (blockIdx.x - 1) * 16;
        sh[tid]        = x[node0 * D_IN + tid];
        sh[tid + 1024] = x[node0 * D_IN + 1024 + tid];
        __syncthreads();
        const int nl = tid >> 6, lane = tid & 63;
        const int node = node0 + nl;
        const float* xr = &sh[nl * D_IN];   // wave-uniform reads -> LDS broadcast
        float acc = encb[lane];
#pragma unroll
        for (int k = 0; k < D_IN; ++k) acc = fmaf(xr[k], encW[k * D + lane], acc);
        b[node * D + lane]  = acc;
        x0[node * D + lane] = acc;
        t0[node * D + lane] = fabsf(acc) + acc;
        // ---------------- count incoming edges ------------------------------
        int e = (blockIdx.x - 1) * 1024 + tid;
        const int stride = 625 * 1024;
        for (; e < N_EDGES; e += stride) atomicAdd(&counts[dst[e]], 1);
    }
}

// ---------------------------------------------------------------------------
// Exclusive scan of counts -> rowptr/cursor.  1024 threads x 10 serial each,
// shfl wave-scan + 16-wave LDS combine: 2 barriers total.
// ---------------------------------------------------------------------------
__global__ void __launch_bounds__(1024) scan_kernel(
    const int* __restrict__ counts, int* __restrict__ rowptr,
    int* __restrict__ cursor) {
    __shared__ int wtot[16];
    const int tid = threadIdx.x;
    const int base = tid * 10;
    int c[10];
    int T = 0;
#pragma unroll
    for (int j = 0; j < 10; ++j) {
        int idx = base + j;
        c[j] = (idx < N_NODES) ? counts[idx] : 0;
        T += c[j];
    }
    int incl = T;                            // wave-inclusive scan
#pragma unroll
    for (int o = 1; o < 64; o <<= 1) {
        int v = __shfl_up(incl, o, 64);
        if ((tid & 63) >= o) incl += v;
    }
    const int wv = tid >> 6;
    if ((tid & 63) == 63) wtot[wv] = incl;
    __syncthreads();
    int wpre = 0;
#pragma unroll
    for (int w2 = 0; w2 < 16; ++w2) wpre += (w2 < wv) ? wtot[w2] : 0;
    int run = wpre + (incl - T);             // global exclusive offset
#pragma unroll
    for (int j = 0; j < 10; ++j) {
        int idx = base + j;
        if (idx < N_NODES) { rowptr[idx] = run; cursor[idx] = run; }
        run += c[j];
    }
    if (tid == 1023) rowptr[N_NODES] = run;  // == N_EDGES
}

__global__ void scatter_kernel(const int* __restrict__ src, const int* __restrict__ dst,
                               const float* __restrict__ ew, int* __restrict__ cursor,
                               uint2* __restrict__ edata) {
    int e = blockIdx.x * blockDim.x + threadIdx.x;
    const int stride = gridDim.x * blockDim.x;
    for (; e < N_EDGES; e += stride) {
        int p = atomicAdd(&cursor[dst[e]], 1);
        edata[p] = make_uint2((unsigned)src[e], __float_as_uint(ew[e]));
    }
}

// ---------------------------------------------------------------------------
// Fused g: F[node] = b + 0.5 * Theta @ (A t_in)[node]   (one wave per node)
// 512-thr blocks (8 nodes) to amortize Th staging; CSR gather unroll-8;
// 64x64 matvec via __shfl broadcast (no Srow LDS, one barrier).
// Optional dual-writes: Xnext = F (init history), t_out = |F| + b (next t).
// ---------------------------------------------------------------------------
__global__ void __launch_bounds__(512) g_kernel(
    const int* __restrict__ rowptr, const uint2* __restrict__ edata,
    const float* __restrict__ t_in, const float* __restrict__ b,
    const float* __restrict__ thetaT, float* __restrict__ F,
    float* __restrict__ Xnext, float* __restrict__ t_out) {
    __shared__ float Th[D * D];
    const int tid = threadIdx.x;
#pragma unroll
    for (int i = 0; i < 2; ++i)              // 4096 floats / 512 thr = 2 float4
        *(float4*)&Th[(i * 512 + tid) * 4] = *(const float4*)&thetaT[(i * 512 + tid) * 4];
    const int ln = tid & 63, wv = tid >> 6;  // 8 waves
    const int node = blockIdx.x * 8 + wv;
    __syncthreads();

    float acc = 0.0f;
    int e = rowptr[node];
    const int end = rowptr[node + 1];
    for (; e + 7 < end; e += 8) {            // unroll-8: 8 gathers in flight
        uint2 a0 = edata[e + 0], a1 = edata[e + 1], a2 = edata[e + 2], a3 = edata[e + 3];
        uint2 a4 = edata[e + 4], a5 = edata[e + 5], a6 = edata[e + 6], a7 = edata[e + 7];
        float v0 = t_in[a0.x * D + ln];
        float v1 = t_in[a1.x * D + ln];
        float v2 = t_in[a2.x * D + ln];
        float v3 = t_in[a3.x * D + ln];
        float v4 = t_in[a4.x * D + ln];
        float v5 = t_in[a5.x * D + ln];
        float v6 = t_in[a6.x * D + ln];
        float v7 = t_in[a7.x * D + ln];
        acc = fmaf(__uint_as_float(a0.y), v0, acc);
        acc = fmaf(__uint_as_float(a1.y), v1, acc);
        acc = fmaf(__uint_as_float(a2.y), v2, acc);
        acc = fmaf(__uint_as_float(a3.y), v3, acc);
        acc = fmaf(__uint_as_float(a4.y), v4, acc);
        acc = fmaf(__uint_as_float(a5.y), v5, acc);
        acc = fmaf(__uint_as_float(a6.y), v6, acc);
        acc = fmaf(__uint_as_float(a7.y), v7, acc);
    }
    for (; e + 3 < end; e += 4) {
        uint2 a0 = edata[e + 0], a1 = edata[e + 1], a2 = edata[e + 2], a3 = edata[e + 3];
        float v0 = t_in[a0.x * D + ln];
        float v1 = t_in[a1.x * D + ln];
        float v2 = t_in[a2.x * D + ln];
        float v3 = t_in[a3.x * D + ln];
        acc = fmaf(__uint_as_float(a0.y), v0, acc);
        acc = fmaf(__uint_as_float(a1.y), v1, acc);
        acc = fmaf(__uint_as_float(a2.y), v2, acc);
        acc = fmaf(__uint_as_float(a3.y), v3, acc);
    }
    for (; e < end; ++e) {
        uint2 a = edata[e];
        acc = fmaf(__uint_as_float(a.y), t_in[a.x * D + ln], acc);
    }

    float r = 0.0f;
#pragma unroll
    for (int k = 0; k < D; ++k) {           // S[k] broadcast via shuffle
        float sk = __shfl(acc, k, 64);
        r = fmaf(sk, Th[k * D + ln], r);
    }
    const float bb = b[node * D + ln];
    const float v = bb + 0.5f * r;
    F[node * D + ln] = v;
    if (Xnext) Xnext[node * D + ln] = v;
    if (t_out) t_out[node * D + ln] = fabsf(v) + bb;
}

// ---------------------------------------------------------------------------
// Anderson: per-block partials of the GG upper triangle (15 entries) in f64.
// float4 streams (10 per iteration) for load efficiency; no global atomics.
// ---------------------------------------------------------------------------
__global__ void gg_kernel(const float* __restrict__ Xb, const float* __restrict__ Fb,
                          double* __restrict__ GGpart) {
    __shared__ double swave[4][16];
    double acc[15];
#pragma unroll
    for (int p = 0; p < 15; p++) acc[p] = 0.0;
    int idx = blockIdx.x * blockDim.x + threadIdx.x;
    const int stride = gridDim.x * blockDim.x;
    for (int i = idx; i < NM / 4; i += stride) {
        float4 g[5];
#pragma unroll
        for (int j = 0; j < 5; j++) {
            const float4 f = ((const float4*)(Fb + j * NM))[i];
            const float4 xv = ((const float4*)(Xb + j * NM))[i];
            g[j] = make_float4(f.x - xv.x, f.y - xv.y, f.z - xv.z, f.w - xv.w);
        }
        int p = 0;
#pragma unroll
        for (int a = 0; a < 5; a++)
#pragma unroll
            for (int bq = a; bq < 5; bq++) {
                acc[p] += (double)g[a].x * (double)g[bq].x
                        + (double)g[a].y * (double)g[bq].y
                        + (double)g[a].z * (double)g[bq].z
                        + (double)g[a].w * (double)g[bq].w;
                p++;
            }
    }
#pragma unroll
    for (int p = 0; p < 15; p++)
        for (int o = 32; o > 0; o >>= 1) acc[p] += __shfl_down(acc[p], o, 64);
    const int wv = threadIdx.x >> 6;
    if ((threadIdx.x & 63) == 0) {
#pragma unroll
        for (int p = 0; p < 15; p++) swave[wv][p] = acc[p];
    }
    __syncthreads();
    if (threadIdx.x < 15) {
        double s = swave[0][threadIdx.x] + swave[1][threadIdx.x] +
                   swave[2][threadIdx.x] + swave[3][threadIdx.x];
        GGpart[blockIdx.x * 16 + threadIdx.x] = s;
    }
}

// ---------------------------------------------------------------------------
// FUSED Anderson combine: every block (1) reduces GGpart (16 lanes/entry,
// identical order in all blocks -> bitwise-identical result), (2) thread 0
// solves (GG + lam I) a = 1, a /= sum(a) in f64, (3) all threads combine
// Xk = sum_j a_j F[j] and (optionally) t = |Xk| + b.
// Removes the single-block solve dispatch entirely.
// ---------------------------------------------------------------------------
__global__ void __launch_bounds__(256) acomb_kernel(
    const double* __restrict__ GGpart, const float* __restrict__ Fb,
    const float* __restrict__ b, float* __restrict__ Xk,
    float* __restrict__ t) {
    __shared__ double GG[16];
    __shared__ float as[5];
    const int tid = threadIdx.x;
    {   // ---- reduce GGpart: entry p = tid>>4, lane-in-group g = tid&15 ----
        const int p = tid >> 4;
        const int g = tid & 15;
        double s = 0.0;
        if (p < 15) {
            for (int blk = g; blk < GG_BLOCKS; blk += 16) s += GGpart[blk * 16 + p];
        }
#pragma unroll
        for (int o = 8; o > 0; o >>= 1) s += __shfl_down(s, o, 16);
        if (g == 0 && p < 15) GG[p] = s;
    }
    __syncthreads();
    if (tid == 0) {   // ---- 5x5 f64 solve with partial pivoting ----
        double A[5][5], rhs[5];
        int q = 0;
        for (int r = 0; r < 5; r++)
            for (int c = r; c < 5; c++) { double v = GG[q++]; A[r][c] = v; A[c][r] = v; }
        for (int i = 0; i < 5; i++) { A[i][i] += 1e-4; rhs[i] = 1.0; }
        for (int i = 0; i < 5; i++) {
            int piv = i; double best = fabs(A[i][i]);
            for (int r = i + 1; r < 5; r++) {
                double v = fabs(A[r][i]);
                if (v > best) { best = v; piv = r; }
            }
            if (piv != i) {
                for (int c = 0; c < 5; c++) { double tmp = A[i][c]; A[i][c] = A[piv][c]; A[piv][c] = tmp; }
                double tr = rhs[i]; rhs[i] = rhs[piv]; rhs[piv] = tr;
            }
            double inv = 1.0 / A[i][i];
            for (int c = 0; c < 5; c++) A[i][c] *= inv;
            rhs[i] *= inv;
            for (int r = 0; r < 5; r++)
                if (r != i) {
                    double f = A[r][i];
                    for (int c = 0; c < 5; c++) A[r][c] -= f * A[i][c];
                    rhs[r] -= f * rhs[i];
                }
        }
        double ssum = rhs[0] + rhs[1] + rhs[2] + rhs[3] + rhs[4];
        for (int j = 0; j < 5; j++) as[j] = (float)(rhs[j] / ssum);
    }
    __syncthreads();
    // ---- combine ----
    int i = blockIdx.x * blockDim.x + tid;
    if (i >= NM / 4) return;
    float4 r = {0.f, 0.f, 0.f, 0.f};
#pragma unroll
    for (int j = 0; j < 5; j++) {
        const float4 f = ((const float4*)(Fb + j * NM))[i];
        float aj = as[j];
        r.x = fmaf(aj, f.x, r.x);
        r.y = fmaf(aj, f.y, r.y);
        r.z = fmaf(aj, f.z, r.z);
        r.w = fmaf(aj, f.w, r.w);
    }
    ((float4*)Xk)[i] = r;
    if (t) {
        const float4 bv = ((const float4*)b)[i];
        float4 tv;
        tv.x = fabsf(r.x) + bv.x;
        tv.y = fabsf(r.y) + bv.y;
        tv.z = fabsf(r.z) + bv.z;
        tv.w = fabsf(r.w) + bv.w;
        ((float4*)t)[i] = tv;
    }
}

// ---------------------------------------------------------------------------
// out[node][o] = sum_d relu(u[node][d]) * decW[d][o]
// ---------------------------------------------------------------------------
__global__ void out_kernel(const float* __restrict__ u, const float* __restrict__ decW,
                           float* __restrict__ out) {
    __shared__ float W[D * D_OUT];
    __shared__ float rows[16][D + 1];
    const int tid = threadIdx.x;
    for (int i = tid; i < D * D_OUT; i += 256) W[i] = decW[i];
    const int node0 = blockIdx.x * 16;
    for (int i = tid; i < 16 * D; i += 256) {
        int n = i >> 6, d = i & 63;
        rows[n][d] = u[(node0 + n) * D + d];
    }
    __syncthreads();
    const int n = tid >> 4, o = tid & 15;
    float acc = 0.0f;
#pragma unroll
    for (int d2 = 0; d2 < D; d2++)
        acc = fmaf(fmaxf(rows[n][d2], 0.0f), W[d2 * D_OUT + o], acc);
    out[(node0 + n) * D_OUT + o] = acc;
}

// ---------------------------------------------------------------------------
extern "C" void kernel_launch(void* const* d_in, const int* in_sizes, int n_in,
                              void* d_out, int out_size, void* d_ws, size_t ws_size,
                              hipStream_t stream) {
    const float* x    = (const float*)d_in[0];
    const int*   ei   = (const int*)d_in[1];
    const float* ew   = (const float*)d_in[2];
    const float* encW = (const float*)d_in[3];
    const float* encb = (const float*)d_in[4];
    const float* cayB = (const float*)d_in[5];
    const float* decW = (const float*)d_in[6];
    float* out = (float*)d_out;
    const int* src = ei;
    const int* dst = ei + N_EDGES;

    char* w = (char*)d_ws;
    double* GGpart = (double*)w;                       // 32768 B
    float*  thetaT = (float*)(w + 33024);              // 16384 B
    int*    counts = (int*)(w + 49408);                // 40000 B
    int*    rowptr = (int*)(w + 89408);                // 40004 B -> pad to 40192
    int*    cursor = (int*)(w + 129600);               // 40000 B -> pad to 40384
    uint2*  edata  = (uint2*)(w + 169984);             // 2560000 B
    float*  b   = (float*)(w + 2729984);
    float*  t0  = b + NM;
    float*  t1  = t0 + NM;
    float*  Xb  = t1 + NM;                             // 5 slots
    float*  Fb  = Xb + 5 * NM;                         // 5 slots

    // setup: theta (block 0) || enc + count (blocks 1..625)
    hipMemsetAsync(counts, 0, N_NODES * sizeof(int), stream);
    setup_kernel<<<626, 1024, 0, stream>>>(cayB, thetaT, x, encW, encb,
                                           b, Xb, t0, dst, counts);
    scan_kernel<<<1, 1024, 0, stream>>>(counts, rowptr, cursor);
    scatter_kernel<<<512, 256, 0, stream>>>(src, dst, ew, cursor, edata);

    const int EW_BLOCKS = (NM / 4 + 255) / 256;   // 625

    // init phase: F[i] = g(X[i]); X[i+1] = F[i]; t ping-pong (g_i reads t_{i%2})
    for (int i = 0; i < 5; i++) {
        float* tin  = (i & 1) ? t1 : t0;
        float* tout = (i < 4) ? ((i & 1) ? t0 : t1) : nullptr;
        g_kernel<<<N_NODES / 8, 512, 0, stream>>>(
            rowptr, edata, tin, b, thetaT, Fb + i * NM,
            (i < 4) ? (Xb + (i + 1) * NM) : nullptr, tout);
    }

    // Anderson phase: gg -> fused (reduce+solve+combine) -> g
    // Last combine (k=4) skips the dead t0 write (no g follows).
    for (int k = 0; k < 5; k++) {
        gg_kernel<<<GG_BLOCKS, 256, 0, stream>>>(Xb, Fb, GGpart);
        acomb_kernel<<<EW_BLOCKS, 256, 0, stream>>>(
            GGpart, Fb, b, Xb + k * NM, (k < 4) ? t0 : nullptr);
        if (k < 4)
            g_kernel<<<N_NODES / 8, 512, 0, stream>>>(
                rowptr, edata, t0, b, thetaT, Fb + k * NM, nullptr, nullptr);
    }

    out_kernel<<<N_NODES / 16, 256, 0, stream>>>(Xb + 4 * NM, decW, out);
}